// Round 1
// baseline (601.505 us; speedup 1.0000x reference)
//
#include <hip/hip_runtime.h>
#include <cstdint>
#include <cstddef>
#include <math.h>

#define EMBED 1024
#define SEQ   2048
#define NROWS 4096   // B*S
#define NHEADS 16

typedef __bf16 bf16x8 __attribute__((ext_vector_type(8)));
typedef float f32x4 __attribute__((ext_vector_type(4)));
typedef unsigned short us8 __attribute__((ext_vector_type(8)));
typedef unsigned short us4 __attribute__((ext_vector_type(4)));

__device__ __forceinline__ unsigned short f2bf(float f) {
  union { float f; unsigned u; } v; v.f = f;
  unsigned r = v.u + 0x7fffu + ((v.u >> 16) & 1u);
  return (unsigned short)(r >> 16);
}

__device__ __forceinline__ bf16x8 as_bf(us8 u) { return __builtin_bit_cast(bf16x8, u); }

__device__ __forceinline__ void gload_lds16(const unsigned short* g, unsigned short* l) {
  __builtin_amdgcn_global_load_lds((const __attribute__((address_space(1))) void*)g,
                                   (__attribute__((address_space(3))) void*)l, 16, 0, 0);
}

// ---------------------------------------------------------------------------
// fp32 [K][N]  ->  bf16 [N][K]   (weight transpose+convert)
// ---------------------------------------------------------------------------
__global__ __launch_bounds__(256) void transpose_to_bf16(
    const float* __restrict__ in, unsigned short* __restrict__ out, int K, int N) {
  __shared__ float tile[32][33];
  const int tx = threadIdx.x & 31, ty = threadIdx.x >> 5;  // 32 x 8
  const int n0 = blockIdx.x * 32, k0 = blockIdx.y * 32;
#pragma unroll
  for (int i = 0; i < 4; i++) {
    int k = ty + i * 8;
    tile[k][tx] = in[(size_t)(k0 + k) * N + n0 + tx];
  }
  __syncthreads();
#pragma unroll
  for (int i = 0; i < 4; i++) {
    int n = ty + i * 8;
    out[(size_t)(n0 + n) * K + k0 + tx] = f2bf(tile[tx][n]);
  }
}

// ---------------------------------------------------------------------------
// LayerNorm: fp32 [rows][1024] -> bf16 [rows][1024].  One wave per row.
// ---------------------------------------------------------------------------
__global__ __launch_bounds__(256) void layernorm_bf16(
    const float* __restrict__ x, const float* __restrict__ g,
    const float* __restrict__ be, unsigned short* __restrict__ out) {
  const int wave = threadIdx.x >> 6, lane = threadIdx.x & 63;
  const int row = blockIdx.x * 4 + wave;
  const float* xr = x + (size_t)row * EMBED;
  float4 v[4];
  float s = 0.f, sq = 0.f;
#pragma unroll
  for (int c = 0; c < 4; c++) {
    v[c] = *(const float4*)&xr[c * 256 + lane * 4];
    s  += v[c].x + v[c].y + v[c].z + v[c].w;
    sq += v[c].x * v[c].x + v[c].y * v[c].y + v[c].z * v[c].z + v[c].w * v[c].w;
  }
#pragma unroll
  for (int m = 1; m < 64; m <<= 1) {
    s  += __shfl_xor(s, m, 64);
    sq += __shfl_xor(sq, m, 64);
  }
  const float mean = s * (1.f / 1024.f);
  const float var  = sq * (1.f / 1024.f) - mean * mean;
  const float rstd = rsqrtf(var + 1e-5f);
#pragma unroll
  for (int c = 0; c < 4; c++) {
    const int idx = c * 256 + lane * 4;
    us4 o;
    o[0] = f2bf((v[c].x - mean) * rstd * g[idx + 0] + be[idx + 0]);
    o[1] = f2bf((v[c].y - mean) * rstd * g[idx + 1] + be[idx + 1]);
    o[2] = f2bf((v[c].z - mean) * rstd * g[idx + 2] + be[idx + 2]);
    o[3] = f2bf((v[c].w - mean) * rstd * g[idx + 3] + be[idx + 3]);
    *(us4*)&out[(size_t)row * EMBED + idx] = o;
  }
}

// ---------------------------------------------------------------------------
// bf16 GEMM, m97 structure: C[M,N] = A[M,K] @ Bt[N,K]^T, 128x128 tile, BK=32.
// MODE_QKV: blockIdx.z in {0,1,2} selects (Wq,bq,q)/(Wk,bk,k)/(Wv,bv,vT);
//           z==2 stores V transposed per head: vT[(b*1024+col)*SEQ + s].
// MODE_WO : no bias, + res(x) -> fp32 out (h)
// MODE_FF1: + bias, exact GELU -> bf16 out
// MODE_FF2: + bias, + res(h) -> fp32 out (d_out)
// ---------------------------------------------------------------------------
enum { MODE_QKV = 0, MODE_WO = 1, MODE_FF1 = 2, MODE_FF2 = 3 };

template <int MODE>
__global__ __launch_bounds__(256) void gemm_bf16(
    const unsigned short* __restrict__ A,
    const unsigned short* __restrict__ Bt0,
    const unsigned short* __restrict__ Bt1,
    const unsigned short* __restrict__ Bt2,
    const float* __restrict__ bias0,
    const float* __restrict__ bias1,
    const float* __restrict__ bias2,
    const float* __restrict__ res,
    void* __restrict__ out0, void* __restrict__ out1, void* __restrict__ out2,
    int M, int N, int K) {
  const unsigned short* Bt = Bt0;
  const float* bias = bias0;
  void* outv = out0;
  int zidx = 0;
  if constexpr (MODE == MODE_QKV) {
    zidx = blockIdx.z;
    if (zidx == 1)      { Bt = Bt1; bias = bias1; outv = out1; }
    else if (zidx == 2) { Bt = Bt2; bias = bias2; outv = out2; }
  }
  __shared__ unsigned short As[128 * 32];
  __shared__ unsigned short Bs[128 * 32];
  const int tid = threadIdx.x;
  const int wave = tid >> 6, lane = tid & 63;
  const int quad = lane >> 4, l15 = lane & 15;
  const int wr = (wave >> 1) * 64, wc = (wave & 1) * 64;
  const int rowA0 = blockIdx.y * 128, colB0 = blockIdx.x * 128;

  const int srow = tid >> 2;
  const int scol = (tid & 3) * 8;
  const unsigned short* gA = A  + (size_t)(rowA0 + srow) * K + scol;
  const unsigned short* gB = Bt + (size_t)(colB0 + srow) * K + scol;
  unsigned short* lA  = &As[tid * 8];
  unsigned short* lA2 = &As[2048 + tid * 8];
  unsigned short* lB  = &Bs[tid * 8];
  unsigned short* lB2 = &Bs[2048 + tid * 8];
  const size_t half = (size_t)64 * K;

  f32x4 acc[4][4];
#pragma unroll
  for (int i = 0; i < 4; i++)
#pragma unroll
    for (int j = 0; j < 4; j++) acc[i][j] = f32x4{0.f, 0.f, 0.f, 0.f};

  for (int k0 = 0; k0 < K; k0 += 32) {
    gload_lds16(gA + k0, lA);
    gload_lds16(gA + half + k0, lA2);
    gload_lds16(gB + k0, lB);
    gload_lds16(gB + half + k0, lB2);
    __syncthreads();
    bf16x8 af[4], bfr[4];
#pragma unroll
    for (int mi = 0; mi < 4; mi++)
      af[mi] = as_bf(*(const us8*)&As[(wr + mi * 16 + l15) * 32 + quad * 8]);
#pragma unroll
    for (int ni = 0; ni < 4; ni++)
      bfr[ni] = as_bf(*(const us8*)&Bs[(wc + ni * 16 + l15) * 32 + quad * 8]);
#pragma unroll
    for (int mi = 0; mi < 4; mi++)
#pragma unroll
      for (int ni = 0; ni < 4; ni++)
        acc[mi][ni] = __builtin_amdgcn_mfma_f32_16x16x32_bf16(af[mi], bfr[ni], acc[mi][ni], 0, 0, 0);
    __syncthreads();
  }

#pragma unroll
  for (int ni = 0; ni < 4; ni++) {
    const int col = colB0 + wc + ni * 16 + l15;
    float bv = 0.f;
    if constexpr (MODE != MODE_WO) bv = bias[col];
#pragma unroll
    for (int mi = 0; mi < 4; mi++) {
      const int row0 = rowA0 + wr + mi * 16 + quad * 4;  // 4 consecutive rows
      if constexpr (MODE == MODE_QKV) {
        unsigned short* o = (unsigned short*)outv;
        if (zidx == 2) {  // V: store transposed per head
          us4 pk;
#pragma unroll
          for (int r = 0; r < 4; r++) pk[r] = f2bf(acc[mi][ni][r] + bv);
          const int bb = row0 >> 11;     // batch (128-row tiles never straddle)
          const int sr = row0 & 2047;    // seq pos
          *(us4*)&o[((size_t)(bb * 1024 + col)) * SEQ + sr] = pk;
        } else {
#pragma unroll
          for (int r = 0; r < 4; r++)
            o[(size_t)(row0 + r) * N + col] = f2bf(acc[mi][ni][r] + bv);
        }
      } else if constexpr (MODE == MODE_FF1) {
        unsigned short* o = (unsigned short*)outv;
#pragma unroll
        for (int r = 0; r < 4; r++) {
          float v = acc[mi][ni][r] + bv;
          v = 0.5f * v * (1.f + erff(v * 0.7071067811865476f));
          o[(size_t)(row0 + r) * N + col] = f2bf(v);
        }
      } else {  // MODE_WO / MODE_FF2 : fp32 out with residual
        float* o = (float*)outv;
#pragma unroll
        for (int r = 0; r < 4; r++) {
          float v = acc[mi][ni][r] + bv + res[(size_t)(row0 + r) * N + col];
          o[(size_t)(row0 + r) * N + col] = v;
        }
      }
    }
  }
}

// ---------------------------------------------------------------------------
// Causal flash attention. Q,K: bf16 [b*S][1024] (head-interleaved).
// Vt: bf16 [b][1024 chan][S].  Z: bf16 [b*S][1024].
// grid (S/64, B*H), block 256 = 4 waves; each wave owns 16 query rows.
// Computes O^T = V^T @ P^T so all MFMA operands load vectorized; P goes
// C-layout -> LDS -> A/B-layout (m120-verified transform).
// ---------------------------------------------------------------------------
__global__ __launch_bounds__(256) void attn_kernel(
    const unsigned short* __restrict__ Q,
    const unsigned short* __restrict__ Kb,
    const unsigned short* __restrict__ Vt,
    unsigned short* __restrict__ Z) {
  __shared__ unsigned short Pl[4][16][72];  // +8 pad: keeps 16B align, kills write conflicts
  __shared__ float Ot[4][64][17];
  const int wave = threadIdx.x >> 6, lane = threadIdx.x & 63;
  const int quad = lane >> 4, l15 = lane & 15;
  const int bh = blockIdx.y, b = bh >> 4, h = bh & 15;
  const int q0 = blockIdx.x * 64 + wave * 16;
  const float cscale = 1.4426950408889634f / 32.f;  // log2(e)/sqrt(EMBED)

  const unsigned short* qp = Q + (size_t)(b * SEQ + q0 + l15) * EMBED + h * 64 + quad * 8;
  const bf16x8 aq0 = as_bf(*(const us8*)qp);
  const bf16x8 aq1 = as_bf(*(const us8*)(qp + 32));

  f32x4 accO[4];
#pragma unroll
  for (int dt = 0; dt < 4; dt++) accO[dt] = f32x4{0.f, 0.f, 0.f, 0.f};
  float mrun[4] = {-INFINITY, -INFINITY, -INFINITY, -INFINITY};
  float lrun[4] = {0.f, 0.f, 0.f, 0.f};

  const int ktmax = (q0 + 15) >> 6;
  for (int kt = 0; kt <= ktmax; kt++) {
    const int kbase = kt * 64;
    f32x4 sf[4];
#pragma unroll
    for (int nt = 0; nt < 4; nt++) {
      const unsigned short* kp =
          Kb + (size_t)(b * SEQ + kbase + nt * 16 + l15) * EMBED + h * 64 + quad * 8;
      const bf16x8 bk0 = as_bf(*(const us8*)kp);
      const bf16x8 bk1 = as_bf(*(const us8*)(kp + 32));
      f32x4 z4 = f32x4{0.f, 0.f, 0.f, 0.f};
      z4 = __builtin_amdgcn_mfma_f32_16x16x32_bf16(aq0, bk0, z4, 0, 0, 0);
      z4 = __builtin_amdgcn_mfma_f32_16x16x32_bf16(aq1, bk1, z4, 0, 0, 0);
      sf[nt] = z4 * cscale;
    }
    if (kt == ktmax) {  // only the boundary tile needs masking
#pragma unroll
      for (int nt = 0; nt < 4; nt++) {
        const int key = kbase + nt * 16 + l15;
#pragma unroll
        for (int r = 0; r < 4; r++)
          if (key > q0 + quad * 4 + r) sf[nt][r] = -INFINITY;
      }
    }
    // row max (row = quad*4+r lives across the 16 lanes of this quad-group)
    float mx[4];
#pragma unroll
    for (int r = 0; r < 4; r++)
      mx[r] = fmaxf(fmaxf(sf[0][r], sf[1][r]), fmaxf(sf[2][r], sf[3][r]));
#pragma unroll
    for (int m = 1; m < 16; m <<= 1)
#pragma unroll
      for (int r = 0; r < 4; r++) mx[r] = fmaxf(mx[r], __shfl_xor(mx[r], m, 16));

    float alpha[4], rs[4] = {0.f, 0.f, 0.f, 0.f};
#pragma unroll
    for (int r = 0; r < 4; r++) {
      const float mnew = fmaxf(mrun[r], mx[r]);
      alpha[r] = exp2f(mrun[r] - mnew);
      mrun[r] = mnew;
    }
#pragma unroll
    for (int nt = 0; nt < 4; nt++)
#pragma unroll
      for (int r = 0; r < 4; r++) {
        const float p = exp2f(sf[nt][r] - mrun[r]);
        sf[nt][r] = p;
        rs[r] += p;
      }
#pragma unroll
    for (int m = 1; m < 16; m <<= 1)
#pragma unroll
      for (int r = 0; r < 4; r++) rs[r] += __shfl_xor(rs[r], m, 16);
#pragma unroll
    for (int r = 0; r < 4; r++) lrun[r] = lrun[r] * alpha[r] + rs[r];

    // P: C-layout -> LDS [q][key]
#pragma unroll
    for (int nt = 0; nt < 4; nt++)
#pragma unroll
      for (int r = 0; r < 4; r++)
        Pl[wave][quad * 4 + r][nt * 16 + l15] = f2bf(sf[nt][r]);

    // broadcast alpha to O^T layout (col q = l15)
    float ab[4];
#pragma unroll
    for (int r = 0; r < 4; r++) ab[r] = __shfl(alpha[r], (l15 >> 2) << 4, 64);
    const int rsel = l15 & 3;
    const float alphaQ = rsel == 0 ? ab[0] : rsel == 1 ? ab[1] : rsel == 2 ? ab[2] : ab[3];
#pragma unroll
    for (int dt = 0; dt < 4; dt++) accO[dt] = accO[dt] * alphaQ;

    const bf16x8 bp0 = as_bf(*(const us8*)&Pl[wave][l15][quad * 8]);
    const bf16x8 bp1 = as_bf(*(const us8*)&Pl[wave][l15][32 + quad * 8]);
#pragma unroll
    for (int dt = 0; dt < 4; dt++) {
      const unsigned short* vp =
          Vt + (size_t)(b * 1024 + h * 64 + dt * 16 + l15) * SEQ + kbase + quad * 8;
      const bf16x8 av0 = as_bf(*(const us8*)vp);
      const bf16x8 av1 = as_bf(*(const us8*)(vp + 32));
      accO[dt] = __builtin_amdgcn_mfma_f32_16x16x32_bf16(av0, bp0, accO[dt], 0, 0, 0);
      accO[dt] = __builtin_amdgcn_mfma_f32_16x16x32_bf16(av1, bp1, accO[dt], 0, 0, 0);
    }
  }

  // epilogue: divide by l, transpose O^T -> O via LDS, store bf16
  float lb[4];
#pragma unroll
  for (int r = 0; r < 4; r++) lb[r] = __shfl(lrun[r], (l15 >> 2) << 4, 64);
  const int rsel = l15 & 3;
  const float lQ = rsel == 0 ? lb[0] : rsel == 1 ? lb[1] : rsel == 2 ? lb[2] : lb[3];
  const float inv = 1.f / lQ;
#pragma unroll
  for (int dt = 0; dt < 4; dt++)
#pragma unroll
    for (int r = 0; r < 4; r++)
      Ot[wave][dt * 16 + quad * 4 + r][l15] = accO[dt][r] * inv;

  const int tq = lane >> 2, dbase = (lane & 3) * 16;
  us8 o0, o1;
#pragma unroll
  for (int i = 0; i < 8; i++) o0[i] = f2bf(Ot[wave][dbase + i][tq]);
#pragma unroll
  for (int i = 0; i < 8; i++) o1[i] = f2bf(Ot[wave][dbase + 8 + i][tq]);
  unsigned short* zp = Z + (size_t)(b * SEQ + q0 + tq) * EMBED + h * 64 + dbase;
  *(us8*)zp = o0;
  *(us8*)(zp + 8) = o1;
}

// ---------------------------------------------------------------------------
extern "C" void kernel_launch(void* const* d_in, const int* in_sizes, int n_in,
                              void* d_out, int out_size, void* d_ws, size_t ws_size,
                              hipStream_t stream) {
  const float* x   = (const float*)d_in[0];
  const float* Wq  = (const float*)d_in[1];
  const float* bq  = (const float*)d_in[2];
  const float* Wk  = (const float*)d_in[3];
  const float* bk  = (const float*)d_in[4];
  const float* Wv  = (const float*)d_in[5];
  const float* bv  = (const float*)d_in[6];
  const float* Wo  = (const float*)d_in[7];
  const float* W1  = (const float*)d_in[8];
  const float* b1  = (const float*)d_in[9];
  const float* W2  = (const float*)d_in[10];
  const float* b2  = (const float*)d_in[11];
  const float* g1  = (const float*)d_in[12];
  const float* be1 = (const float*)d_in[13];
  const float* g2  = (const float*)d_in[14];
  const float* be2 = (const float*)d_in[15];
  float* out = (float*)d_out;

  char* ws = (char*)d_ws;
  const size_t MB = 1024 * 1024;
  unsigned short* wqT = (unsigned short*)(ws + 0 * MB);   // 2 MB
  unsigned short* wkT = (unsigned short*)(ws + 2 * MB);   // 2 MB
  unsigned short* wvT = (unsigned short*)(ws + 4 * MB);   // 2 MB
  unsigned short* woT = (unsigned short*)(ws + 6 * MB);   // 2 MB
  unsigned short* w1T = (unsigned short*)(ws + 8 * MB);   // 8 MB
  unsigned short* w2T = (unsigned short*)(ws + 16 * MB);  // 8 MB
  float*          hb  = (float*)         (ws + 24 * MB);  // 16 MB
  unsigned short* ln1 = (unsigned short*)(ws + 40 * MB);  // 8 MB (dead after V gemm)
  unsigned short* qb  = (unsigned short*)(ws + 48 * MB);  // 8 MB (dead after attn)
  unsigned short* kb2 = (unsigned short*)(ws + 56 * MB);  // 8 MB (dead after attn)
  unsigned short* vT  = (unsigned short*)(ws + 64 * MB);  // 8 MB (dead after attn)
  unsigned short* zb  = (unsigned short*)(ws + 72 * MB);  // 8 MB (dead after Wo)
  unsigned short* ln2 = (unsigned short*)(ws + 80 * MB);  // 8 MB
  unsigned short* m1  = (unsigned short*)(ws + 40 * MB);  // 32 MB, aliases ln1/q/k/vT (all dead)
  (void)in_sizes; (void)n_in; (void)out_size; (void)ws_size;

  // weight transposes (fp32 [K][N] -> bf16 [N][K])
  transpose_to_bf16<<<dim3(32, 32), 256, 0, stream>>>(Wq, wqT, 1024, 1024);
  transpose_to_bf16<<<dim3(32, 32), 256, 0, stream>>>(Wk, wkT, 1024, 1024);
  transpose_to_bf16<<<dim3(32, 32), 256, 0, stream>>>(Wv, wvT, 1024, 1024);
  transpose_to_bf16<<<dim3(32, 32), 256, 0, stream>>>(Wo, woT, 1024, 1024);
  transpose_to_bf16<<<dim3(128, 32), 256, 0, stream>>>(W1, w1T, 1024, 4096);
  transpose_to_bf16<<<dim3(32, 128), 256, 0, stream>>>(W2, w2T, 4096, 1024);

  layernorm_bf16<<<NROWS / 4, 256, 0, stream>>>(x, g1, be1, ln1);

  gemm_bf16<MODE_QKV><<<dim3(8, 32, 3), 256, 0, stream>>>(
      ln1, wqT, wkT, wvT, bq, bk, bv, nullptr, qb, kb2, vT, NROWS, 1024, 1024);

  attn_kernel<<<dim3(SEQ / 64, 32), 256, 0, stream>>>(qb, kb2, vT, zb);

  gemm_bf16<MODE_WO><<<dim3(8, 32), 256, 0, stream>>>(
      zb, woT, nullptr, nullptr, nullptr, nullptr, nullptr, x, hb, nullptr, nullptr,
      NROWS, 1024, 1024);

  layernorm_bf16<<<NROWS / 4, 256, 0, stream>>>(hb, g2, be2, ln2);

  gemm_bf16<MODE_FF1><<<dim3(32, 32), 256, 0, stream>>>(
      ln2, w1T, nullptr, nullptr, b1, nullptr, nullptr, nullptr, m1, nullptr, nullptr,
      NROWS, 4096, 1024);

  gemm_bf16<MODE_FF2><<<dim3(8, 32), 256, 0, stream>>>(
      m1, w2T, nullptr, nullptr, b2, nullptr, nullptr, hb, out, nullptr, nullptr,
      NROWS, 1024, 4096);
}

// Round 2
// 460.338 us; speedup vs baseline: 1.3067x; 1.3067x over previous
//
#include <hip/hip_runtime.h>
#include <cstdint>
#include <cstddef>
#include <math.h>

#define EMBED 1024
#define SEQ   2048
#define NROWS 4096   // B*S
#define NHEADS 16

typedef __bf16 bf16x8 __attribute__((ext_vector_type(8)));
typedef float f32x4 __attribute__((ext_vector_type(4)));
typedef unsigned short us8 __attribute__((ext_vector_type(8)));
typedef unsigned short us4 __attribute__((ext_vector_type(4)));

__device__ __forceinline__ unsigned short f2bf(float f) {
  union { float f; unsigned u; } v; v.f = f;
  unsigned r = v.u + 0x7fffu + ((v.u >> 16) & 1u);
  return (unsigned short)(r >> 16);
}

__device__ __forceinline__ bf16x8 as_bf(us8 u) { return __builtin_bit_cast(bf16x8, u); }

__device__ __forceinline__ void gload_lds16(const unsigned short* g, unsigned short* l) {
  __builtin_amdgcn_global_load_lds((const __attribute__((address_space(1))) void*)g,
                                   (__attribute__((address_space(3))) void*)l, 16, 0, 0);
}

// ---------------------------------------------------------------------------
// fp32 [K][N]  ->  bf16 [N][K]   (weight transpose+convert)
// ---------------------------------------------------------------------------
__global__ __launch_bounds__(256) void transpose_to_bf16(
    const float* __restrict__ in, unsigned short* __restrict__ out, int K, int N) {
  __shared__ float tile[32][33];
  const int tx = threadIdx.x & 31, ty = threadIdx.x >> 5;  // 32 x 8
  const int n0 = blockIdx.x * 32, k0 = blockIdx.y * 32;
#pragma unroll
  for (int i = 0; i < 4; i++) {
    int k = ty + i * 8;
    tile[k][tx] = in[(size_t)(k0 + k) * N + n0 + tx];
  }
  __syncthreads();
#pragma unroll
  for (int i = 0; i < 4; i++) {
    int n = ty + i * 8;
    out[(size_t)(n0 + n) * K + k0 + tx] = f2bf(tile[tx][n]);
  }
}

// ---------------------------------------------------------------------------
// LayerNorm: fp32 [rows][1024] -> bf16 [rows][1024].  One wave per row.
// ---------------------------------------------------------------------------
__global__ __launch_bounds__(256) void layernorm_bf16(
    const float* __restrict__ x, const float* __restrict__ g,
    const float* __restrict__ be, unsigned short* __restrict__ out) {
  const int wave = threadIdx.x >> 6, lane = threadIdx.x & 63;
  const int row = blockIdx.x * 4 + wave;
  const float* xr = x + (size_t)row * EMBED;
  float4 v[4];
  float s = 0.f, sq = 0.f;
#pragma unroll
  for (int c = 0; c < 4; c++) {
    v[c] = *(const float4*)&xr[c * 256 + lane * 4];
    s  += v[c].x + v[c].y + v[c].z + v[c].w;
    sq += v[c].x * v[c].x + v[c].y * v[c].y + v[c].z * v[c].z + v[c].w * v[c].w;
  }
#pragma unroll
  for (int m = 1; m < 64; m <<= 1) {
    s  += __shfl_xor(s, m, 64);
    sq += __shfl_xor(sq, m, 64);
  }
  const float mean = s * (1.f / 1024.f);
  const float var  = sq * (1.f / 1024.f) - mean * mean;
  const float rstd = rsqrtf(var + 1e-5f);
#pragma unroll
  for (int c = 0; c < 4; c++) {
    const int idx = c * 256 + lane * 4;
    us4 o;
    o[0] = f2bf((v[c].x - mean) * rstd * g[idx + 0] + be[idx + 0]);
    o[1] = f2bf((v[c].y - mean) * rstd * g[idx + 1] + be[idx + 1]);
    o[2] = f2bf((v[c].z - mean) * rstd * g[idx + 2] + be[idx + 2]);
    o[3] = f2bf((v[c].w - mean) * rstd * g[idx + 3] + be[idx + 3]);
    *(us4*)&out[(size_t)row * EMBED + idx] = o;
  }
}

// ---------------------------------------------------------------------------
// bf16 GEMM, m97 structure: C[M,N] = A[M,K] @ Bt[N,K]^T, 128x128 tile, BK=32.
// ---------------------------------------------------------------------------
enum { MODE_QKV = 0, MODE_WO = 1, MODE_FF1 = 2, MODE_FF2 = 3 };

template <int MODE>
__global__ __launch_bounds__(256) void gemm_bf16(
    const unsigned short* __restrict__ A,
    const unsigned short* __restrict__ Bt0,
    const unsigned short* __restrict__ Bt1,
    const unsigned short* __restrict__ Bt2,
    const float* __restrict__ bias0,
    const float* __restrict__ bias1,
    const float* __restrict__ bias2,
    const float* __restrict__ res,
    void* __restrict__ out0, void* __restrict__ out1, void* __restrict__ out2,
    int M, int N, int K) {
  const unsigned short* Bt = Bt0;
  const float* bias = bias0;
  void* outv = out0;
  int zidx = 0;
  if constexpr (MODE == MODE_QKV) {
    zidx = blockIdx.z;
    if (zidx == 1)      { Bt = Bt1; bias = bias1; outv = out1; }
    else if (zidx == 2) { Bt = Bt2; bias = bias2; outv = out2; }
  }
  __shared__ unsigned short As[128 * 32];
  __shared__ unsigned short Bs[128 * 32];
  const int tid = threadIdx.x;
  const int wave = tid >> 6, lane = tid & 63;
  const int quad = lane >> 4, l15 = lane & 15;
  const int wr = (wave >> 1) * 64, wc = (wave & 1) * 64;
  const int rowA0 = blockIdx.y * 128, colB0 = blockIdx.x * 128;

  const int srow = tid >> 2;
  const int scol = (tid & 3) * 8;
  const unsigned short* gA = A  + (size_t)(rowA0 + srow) * K + scol;
  const unsigned short* gB = Bt + (size_t)(colB0 + srow) * K + scol;
  unsigned short* lA  = &As[tid * 8];
  unsigned short* lA2 = &As[2048 + tid * 8];
  unsigned short* lB  = &Bs[tid * 8];
  unsigned short* lB2 = &Bs[2048 + tid * 8];
  const size_t half = (size_t)64 * K;

  f32x4 acc[4][4];
#pragma unroll
  for (int i = 0; i < 4; i++)
#pragma unroll
    for (int j = 0; j < 4; j++) acc[i][j] = f32x4{0.f, 0.f, 0.f, 0.f};

  for (int k0 = 0; k0 < K; k0 += 32) {
    gload_lds16(gA + k0, lA);
    gload_lds16(gA + half + k0, lA2);
    gload_lds16(gB + k0, lB);
    gload_lds16(gB + half + k0, lB2);
    __syncthreads();
    bf16x8 af[4], bfr[4];
#pragma unroll
    for (int mi = 0; mi < 4; mi++)
      af[mi] = as_bf(*(const us8*)&As[(wr + mi * 16 + l15) * 32 + quad * 8]);
#pragma unroll
    for (int ni = 0; ni < 4; ni++)
      bfr[ni] = as_bf(*(const us8*)&Bs[(wc + ni * 16 + l15) * 32 + quad * 8]);
#pragma unroll
    for (int mi = 0; mi < 4; mi++)
#pragma unroll
      for (int ni = 0; ni < 4; ni++)
        acc[mi][ni] = __builtin_amdgcn_mfma_f32_16x16x32_bf16(af[mi], bfr[ni], acc[mi][ni], 0, 0, 0);
    __syncthreads();
  }

#pragma unroll
  for (int ni = 0; ni < 4; ni++) {
    const int col = colB0 + wc + ni * 16 + l15;
    float bv = 0.f;
    if constexpr (MODE != MODE_WO) bv = bias[col];
#pragma unroll
    for (int mi = 0; mi < 4; mi++) {
      const int row0 = rowA0 + wr + mi * 16 + quad * 4;  // 4 consecutive rows
      if constexpr (MODE == MODE_QKV) {
        unsigned short* o = (unsigned short*)outv;
        if (zidx == 2) {  // V: store transposed per head
          us4 pk;
#pragma unroll
          for (int r = 0; r < 4; r++) pk[r] = f2bf(acc[mi][ni][r] + bv);
          const int bb = row0 >> 11;     // batch (128-row tiles never straddle)
          const int sr = row0 & 2047;    // seq pos
          *(us4*)&o[((size_t)(bb * 1024 + col)) * SEQ + sr] = pk;
        } else {
#pragma unroll
          for (int r = 0; r < 4; r++)
            o[(size_t)(row0 + r) * N + col] = f2bf(acc[mi][ni][r] + bv);
        }
      } else if constexpr (MODE == MODE_FF1) {
        unsigned short* o = (unsigned short*)outv;
#pragma unroll
        for (int r = 0; r < 4; r++) {
          float v = acc[mi][ni][r] + bv;
          v = 0.5f * v * (1.f + erff(v * 0.7071067811865476f));
          o[(size_t)(row0 + r) * N + col] = f2bf(v);
        }
      } else {  // MODE_WO / MODE_FF2 : fp32 out with residual
        float* o = (float*)outv;
#pragma unroll
        for (int r = 0; r < 4; r++) {
          float v = acc[mi][ni][r] + bv + res[(size_t)(row0 + r) * N + col];
          o[(size_t)(row0 + r) * N + col] = v;
        }
      }
    }
  }
}

// ---------------------------------------------------------------------------
// Causal flash attention, S^T orientation.
// Q,K: bf16 [b*S][1024] (head-interleaved).  Vt: bf16 [b][1024 chan][S].
// Z: bf16 [b*S][1024].
// grid (B*H=32, S/128=16), block 256 = 4 waves; wave w owns q rows
// [qt*128 + w*32, +32) as two 16-row chunks.  Per 64-key tile:
//   - K tile [key][d] and V^T tile [d][key] staged to LDS (global_load_lds,
//     m97 64B-row layout), shared by all 4 waves.
//   - S^T = K·Q^T via mfma(A=K, B=Q): C cols = q = lane&15 -> softmax stats
//     per-lane, only 2 shuffle steps (xor16/xor32), alpha/l rescale in-lane.
//   - P^T packed to LDS [q][key] with us4 writes, read back as B-frags (b128),
//     O^T accumulated via mfma(A=V^T, B=P^T) — same C col = q = lane&15.
// ---------------------------------------------------------------------------
__global__ __launch_bounds__(256) void attn_kernel(
    const unsigned short* __restrict__ Q,
    const unsigned short* __restrict__ Kb,
    const unsigned short* __restrict__ Vt,
    unsigned short* __restrict__ Z) {
  __shared__ unsigned short Ksh[2][64][32];  // [d-half][key][32 d]
  __shared__ unsigned short Vsh[2][64][32];  // [key-half][d][32 key]
  __shared__ unsigned short Pt[4][16][72];   // per wave: [q][64 key + pad]
  __shared__ float Ot[4][64][17];            // per wave: [d][16 q + pad]

  const int wave = threadIdx.x >> 6, lane = threadIdx.x & 63;
  const int quad = lane >> 4, l15 = lane & 15;
  const int bh = blockIdx.x, b = bh >> 4, h = bh & 15;
  const int qt = blockIdx.y;
  const int q0 = qt * 128 + wave * 32;
  const float cscale = 1.4426950408889634f / 32.f;  // log2(e)/sqrt(EMBED)

  // Q B-frags (B[k=d][n=q]: lane = q, quad*8+j = d): [chunk][d-half]
  bf16x8 qf[2][2];
#pragma unroll
  for (int c = 0; c < 2; c++)
#pragma unroll
    for (int kf = 0; kf < 2; kf++)
      qf[c][kf] = as_bf(*(const us8*)&Q[(size_t)(b * SEQ + q0 + c * 16 + l15) * EMBED +
                                        h * 64 + kf * 32 + quad * 8]);

  f32x4 accO[2][4];
#pragma unroll
  for (int c = 0; c < 2; c++)
#pragma unroll
    for (int dt = 0; dt < 4; dt++) accO[c][dt] = f32x4{0.f, 0.f, 0.f, 0.f};
  float mrun[2] = {-INFINITY, -INFINITY};
  float lrun[2] = {0.f, 0.f};

  const int ls_row = lane >> 2;   // 0..15: row within this wave's 16-row stage group
  const int ls_c16 = lane & 3;    // 16B chunk within 64B half-row
  const int nkt = 2 * qt + 2;

  for (int kt = 0; kt < nkt; kt++) {
    const int kbase = kt * 64;
    // ---- stage K rows [wave*16, +16) and V^T rows [wave*16, +16) ----
    const int krow = wave * 16 + ls_row;
#pragma unroll
    for (int kf = 0; kf < 2; kf++) {
      const unsigned short* g =
          &Kb[(size_t)(b * SEQ + kbase + krow) * EMBED + h * 64 + kf * 32 + ls_c16 * 8];
      gload_lds16(g, &Ksh[kf][wave * 16][0] + lane * 8);
    }
#pragma unroll
    for (int kk = 0; kk < 2; kk++) {
      const unsigned short* g =
          &Vt[(size_t)(b * 1024 + h * 64 + krow) * SEQ + kbase + kk * 32 + ls_c16 * 8];
      gload_lds16(g, &Vsh[kk][wave * 16][0] + lane * 8);
    }
    __syncthreads();

#pragma unroll
    for (int c = 0; c < 2; c++) {
      const int qc = q0 + c * 16;
      if (kbase > qc + 15) continue;  // fully masked chunk (wave-uniform branch)
      // ---- S^T = K · Q^T ----
      f32x4 sf[4];
#pragma unroll
      for (int nt = 0; nt < 4; nt++) {
        f32x4 z4 = f32x4{0.f, 0.f, 0.f, 0.f};
#pragma unroll
        for (int kf = 0; kf < 2; kf++) {
          const bf16x8 ka = as_bf(*(const us8*)&Ksh[kf][nt * 16 + l15][quad * 8]);
          z4 = __builtin_amdgcn_mfma_f32_16x16x32_bf16(ka, qf[c][kf], z4, 0, 0, 0);
        }
        sf[nt] = z4 * cscale;
      }
      // ---- causal mask (boundary tiles only): key > q -> -inf ----
      if (kbase + 63 > qc) {
        const int q = qc + l15;
#pragma unroll
        for (int nt = 0; nt < 4; nt++) {
          const int key0 = kbase + nt * 16 + quad * 4;
#pragma unroll
          for (int r = 0; r < 4; r++)
            if (key0 + r > q) sf[nt][r] = -INFINITY;
        }
      }
      // ---- online softmax: stats per q = per lane ----
      float mx = sf[0][0];
#pragma unroll
      for (int nt = 0; nt < 4; nt++)
#pragma unroll
        for (int r = 0; r < 4; r++) mx = fmaxf(mx, sf[nt][r]);
      mx = fmaxf(mx, __shfl_xor(mx, 16, 64));
      mx = fmaxf(mx, __shfl_xor(mx, 32, 64));
      const float mnew = fmaxf(mrun[c], mx);
      const float alpha = exp2f(mrun[c] - mnew);
      mrun[c] = mnew;
      float rs = 0.f;
#pragma unroll
      for (int nt = 0; nt < 4; nt++) {
        us4 pk;
#pragma unroll
        for (int r = 0; r < 4; r++) {
          const float p = exp2f(sf[nt][r] - mnew);
          rs += p;
          pk[r] = f2bf(p);
        }
        *(us4*)&Pt[wave][l15][nt * 16 + quad * 4] = pk;
      }
      rs += __shfl_xor(rs, 16, 64);
      rs += __shfl_xor(rs, 32, 64);
      lrun[c] = lrun[c] * alpha + rs;
#pragma unroll
      for (int dt = 0; dt < 4; dt++) accO[c][dt] = accO[c][dt] * alpha;
      // ---- O^T += V^T · P^T ----
      bf16x8 pf[2];
#pragma unroll
      for (int kk = 0; kk < 2; kk++)
        pf[kk] = as_bf(*(const us8*)&Pt[wave][l15][kk * 32 + quad * 8]);
#pragma unroll
      for (int dt = 0; dt < 4; dt++)
#pragma unroll
        for (int kk = 0; kk < 2; kk++) {
          const bf16x8 va = as_bf(*(const us8*)&Vsh[kk][dt * 16 + l15][quad * 8]);
          accO[c][dt] = __builtin_amdgcn_mfma_f32_16x16x32_bf16(va, pf[kk], accO[c][dt], 0, 0, 0);
        }
    }
    __syncthreads();
  }

  // ---- epilogue: /l, transpose O^T -> O via per-wave LDS, store bf16 ----
#pragma unroll
  for (int c = 0; c < 2; c++) {
    const float inv = 1.f / lrun[c];
#pragma unroll
    for (int dt = 0; dt < 4; dt++)
#pragma unroll
      for (int r = 0; r < 4; r++)
        Ot[wave][dt * 16 + quad * 4 + r][l15] = accO[c][dt][r] * inv;
    const int lq = lane >> 2, dbase = (lane & 3) * 16;
    us8 o0, o1;
#pragma unroll
    for (int i = 0; i < 8; i++) o0[i] = f2bf(Ot[wave][dbase + i][lq]);
#pragma unroll
    for (int i = 0; i < 8; i++) o1[i] = f2bf(Ot[wave][dbase + 8 + i][lq]);
    unsigned short* zp = Z + (size_t)(b * SEQ + q0 + c * 16 + lq) * EMBED + h * 64 + dbase;
    *(us8*)zp = o0;
    *(us8*)(zp + 8) = o1;
  }
}

// ---------------------------------------------------------------------------
extern "C" void kernel_launch(void* const* d_in, const int* in_sizes, int n_in,
                              void* d_out, int out_size, void* d_ws, size_t ws_size,
                              hipStream_t stream) {
  const float* x   = (const float*)d_in[0];
  const float* Wq  = (const float*)d_in[1];
  const float* bq  = (const float*)d_in[2];
  const float* Wk  = (const float*)d_in[3];
  const float* bk  = (const float*)d_in[4];
  const float* Wv  = (const float*)d_in[5];
  const float* bv  = (const float*)d_in[6];
  const float* Wo  = (const float*)d_in[7];
  const float* W1  = (const float*)d_in[8];
  const float* b1  = (const float*)d_in[9];
  const float* W2  = (const float*)d_in[10];
  const float* b2  = (const float*)d_in[11];
  const float* g1  = (const float*)d_in[12];
  const float* be1 = (const float*)d_in[13];
  const float* g2  = (const float*)d_in[14];
  const float* be2 = (const float*)d_in[15];
  float* out = (float*)d_out;

  char* ws = (char*)d_ws;
  const size_t MB = 1024 * 1024;
  unsigned short* wqT = (unsigned short*)(ws + 0 * MB);   // 2 MB
  unsigned short* wkT = (unsigned short*)(ws + 2 * MB);   // 2 MB
  unsigned short* wvT = (unsigned short*)(ws + 4 * MB);   // 2 MB
  unsigned short* woT = (unsigned short*)(ws + 6 * MB);   // 2 MB
  unsigned short* w1T = (unsigned short*)(ws + 8 * MB);   // 8 MB
  unsigned short* w2T = (unsigned short*)(ws + 16 * MB);  // 8 MB
  float*          hb  = (float*)         (ws + 24 * MB);  // 16 MB
  unsigned short* ln1 = (unsigned short*)(ws + 40 * MB);  // 8 MB (dead after QKV gemm)
  unsigned short* qb  = (unsigned short*)(ws + 48 * MB);  // 8 MB (dead after attn)
  unsigned short* kb2 = (unsigned short*)(ws + 56 * MB);  // 8 MB (dead after attn)
  unsigned short* vT  = (unsigned short*)(ws + 64 * MB);  // 8 MB (dead after attn)
  unsigned short* zb  = (unsigned short*)(ws + 72 * MB);  // 8 MB (dead after Wo)
  unsigned short* ln2 = (unsigned short*)(ws + 80 * MB);  // 8 MB
  unsigned short* m1  = (unsigned short*)(ws + 40 * MB);  // 32 MB, aliases ln1/q/k/vT
  (void)in_sizes; (void)n_in; (void)out_size; (void)ws_size;

  transpose_to_bf16<<<dim3(32, 32), 256, 0, stream>>>(Wq, wqT, 1024, 1024);
  transpose_to_bf16<<<dim3(32, 32), 256, 0, stream>>>(Wk, wkT, 1024, 1024);
  transpose_to_bf16<<<dim3(32, 32), 256, 0, stream>>>(Wv, wvT, 1024, 1024);
  transpose_to_bf16<<<dim3(32, 32), 256, 0, stream>>>(Wo, woT, 1024, 1024);
  transpose_to_bf16<<<dim3(128, 32), 256, 0, stream>>>(W1, w1T, 1024, 4096);
  transpose_to_bf16<<<dim3(32, 128), 256, 0, stream>>>(W2, w2T, 4096, 1024);

  layernorm_bf16<<<NROWS / 4, 256, 0, stream>>>(x, g1, be1, ln1);

  gemm_bf16<MODE_QKV><<<dim3(8, 32, 3), 256, 0, stream>>>(
      ln1, wqT, wkT, wvT, bq, bk, bv, nullptr, qb, kb2, vT, NROWS, 1024, 1024);

  attn_kernel<<<dim3(32, 16), 256, 0, stream>>>(qb, kb2, vT, zb);

  gemm_bf16<MODE_WO><<<dim3(8, 32), 256, 0, stream>>>(
      zb, woT, nullptr, nullptr, nullptr, nullptr, nullptr, x, hb, nullptr, nullptr,
      NROWS, 1024, 1024);

  layernorm_bf16<<<NROWS / 4, 256, 0, stream>>>(hb, g2, be2, ln2);

  gemm_bf16<MODE_FF1><<<dim3(32, 32), 256, 0, stream>>>(
      ln2, w1T, nullptr, nullptr, b1, nullptr, nullptr, nullptr, m1, nullptr, nullptr,
      NROWS, 4096, 1024);

  gemm_bf16<MODE_FF2><<<dim3(8, 32), 256, 0, stream>>>(
      m1, w2T, nullptr, nullptr, b2, nullptr, nullptr, hb, out, nullptr, nullptr,
      NROWS, 1024, 4096);
}

// Round 3
// 439.037 us; speedup vs baseline: 1.3701x; 1.0485x over previous
//
#include <hip/hip_runtime.h>
#include <cstdint>
#include <cstddef>
#include <math.h>

#define EMBED 1024
#define SEQ   2048
#define NROWS 4096   // B*S
#define NHEADS 16

typedef __bf16 bf16x8 __attribute__((ext_vector_type(8)));
typedef float f32x4 __attribute__((ext_vector_type(4)));
typedef unsigned short us8 __attribute__((ext_vector_type(8)));
typedef unsigned short us4 __attribute__((ext_vector_type(4)));

__device__ __forceinline__ unsigned short f2bf(float f) {
  union { float f; unsigned u; } v; v.f = f;
  unsigned r = v.u + 0x7fffu + ((v.u >> 16) & 1u);
  return (unsigned short)(r >> 16);
}
__device__ __forceinline__ float bf2f(unsigned short u) {
  union { unsigned u; float f; } v; v.u = (unsigned)u << 16; return v.f;
}

__device__ __forceinline__ bf16x8 as_bf(us8 u) { return __builtin_bit_cast(bf16x8, u); }

__device__ __forceinline__ void gload_lds16(const unsigned short* g, unsigned short* l) {
  __builtin_amdgcn_global_load_lds((const __attribute__((address_space(1))) void*)g,
                                   (__attribute__((address_space(3))) void*)l, 16, 0, 0);
}

// ---------------------------------------------------------------------------
// fp32 [K][N]  ->  bf16 [N][K]   (weight transpose+convert)
// ---------------------------------------------------------------------------
__global__ __launch_bounds__(256) void transpose_to_bf16(
    const float* __restrict__ in, unsigned short* __restrict__ out, int K, int N) {
  __shared__ float tile[32][33];
  const int tx = threadIdx.x & 31, ty = threadIdx.x >> 5;  // 32 x 8
  const int n0 = blockIdx.x * 32, k0 = blockIdx.y * 32;
#pragma unroll
  for (int i = 0; i < 4; i++) {
    int k = ty + i * 8;
    tile[k][tx] = in[(size_t)(k0 + k) * N + n0 + tx];
  }
  __syncthreads();
#pragma unroll
  for (int i = 0; i < 4; i++) {
    int n = ty + i * 8;
    out[(size_t)(n0 + n) * K + k0 + tx] = f2bf(tile[tx][n]);
  }
}

// ---------------------------------------------------------------------------
// LayerNorm: fp32 [rows][1024] -> bf16 [rows][1024].  One wave per row.
// ---------------------------------------------------------------------------
__global__ __launch_bounds__(256) void layernorm_bf16(
    const float* __restrict__ x, const float* __restrict__ g,
    const float* __restrict__ be, unsigned short* __restrict__ out) {
  const int wave = threadIdx.x >> 6, lane = threadIdx.x & 63;
  const int row = blockIdx.x * 4 + wave;
  const float* xr = x + (size_t)row * EMBED;
  float4 v[4];
  float s = 0.f, sq = 0.f;
#pragma unroll
  for (int c = 0; c < 4; c++) {
    v[c] = *(const float4*)&xr[c * 256 + lane * 4];
    s  += v[c].x + v[c].y + v[c].z + v[c].w;
    sq += v[c].x * v[c].x + v[c].y * v[c].y + v[c].z * v[c].z + v[c].w * v[c].w;
  }
#pragma unroll
  for (int m = 1; m < 64; m <<= 1) {
    s  += __shfl_xor(s, m, 64);
    sq += __shfl_xor(sq, m, 64);
  }
  const float mean = s * (1.f / 1024.f);
  const float var  = sq * (1.f / 1024.f) - mean * mean;
  const float rstd = rsqrtf(var + 1e-5f);
#pragma unroll
  for (int c = 0; c < 4; c++) {
    const int idx = c * 256 + lane * 4;
    us4 o;
    o[0] = f2bf((v[c].x - mean) * rstd * g[idx + 0] + be[idx + 0]);
    o[1] = f2bf((v[c].y - mean) * rstd * g[idx + 1] + be[idx + 1]);
    o[2] = f2bf((v[c].z - mean) * rstd * g[idx + 2] + be[idx + 2]);
    o[3] = f2bf((v[c].w - mean) * rstd * g[idx + 3] + be[idx + 3]);
    *(us4*)&out[(size_t)row * EMBED + idx] = o;
  }
}

// ---------------------------------------------------------------------------
// bf16 GEMM, m97 structure: C[M,N] = A[M,K] @ Bt[N,K]^T, 128x128 tile, BK=32.
// MODE_PART: split-K — blockIdx.z selects K-slice [z*1024, +1024) and partial
//            output buffer (out0..out3); stores raw acc as bf16 (no bias/res).
// ---------------------------------------------------------------------------
enum { MODE_QKV = 0, MODE_WO = 1, MODE_FF1 = 2, MODE_FF2 = 3, MODE_PART = 4 };

template <int MODE>
__global__ __launch_bounds__(256) void gemm_bf16(
    const unsigned short* __restrict__ A,
    const unsigned short* __restrict__ Bt0,
    const unsigned short* __restrict__ Bt1,
    const unsigned short* __restrict__ Bt2,
    const float* __restrict__ bias0,
    const float* __restrict__ bias1,
    const float* __restrict__ bias2,
    const float* __restrict__ res,
    void* __restrict__ out0, void* __restrict__ out1,
    void* __restrict__ out2, void* __restrict__ out3,
    int M, int N, int K) {
  const unsigned short* Bt = Bt0;
  const float* bias = bias0;
  void* outv = out0;
  int zidx = 0;
  if constexpr (MODE == MODE_QKV) {
    zidx = blockIdx.z;
    if (zidx == 1)      { Bt = Bt1; bias = bias1; outv = out1; }
    else if (zidx == 2) { Bt = Bt2; bias = bias2; outv = out2; }
  }
  if constexpr (MODE == MODE_PART) {
    zidx = blockIdx.z;
    outv = (zidx == 0) ? out0 : (zidx == 1) ? out1 : (zidx == 2) ? out2 : out3;
  }
  const int Ksub = (MODE == MODE_PART) ? 1024 : K;
  const int koff = (MODE == MODE_PART) ? zidx * 1024 : 0;

  __shared__ unsigned short As[128 * 32];
  __shared__ unsigned short Bs[128 * 32];
  const int tid = threadIdx.x;
  const int wave = tid >> 6, lane = tid & 63;
  const int quad = lane >> 4, l15 = lane & 15;
  const int wr = (wave >> 1) * 64, wc = (wave & 1) * 64;
  const int rowA0 = blockIdx.y * 128, colB0 = blockIdx.x * 128;

  const int srow = tid >> 2;
  const int scol = (tid & 3) * 8;
  const unsigned short* gA = A  + (size_t)(rowA0 + srow) * K + koff + scol;
  const unsigned short* gB = Bt + (size_t)(colB0 + srow) * K + koff + scol;
  unsigned short* lA  = &As[tid * 8];
  unsigned short* lA2 = &As[2048 + tid * 8];
  unsigned short* lB  = &Bs[tid * 8];
  unsigned short* lB2 = &Bs[2048 + tid * 8];
  const size_t half = (size_t)64 * K;

  f32x4 acc[4][4];
#pragma unroll
  for (int i = 0; i < 4; i++)
#pragma unroll
    for (int j = 0; j < 4; j++) acc[i][j] = f32x4{0.f, 0.f, 0.f, 0.f};

  for (int k0 = 0; k0 < Ksub; k0 += 32) {
    gload_lds16(gA + k0, lA);
    gload_lds16(gA + half + k0, lA2);
    gload_lds16(gB + k0, lB);
    gload_lds16(gB + half + k0, lB2);
    __syncthreads();
    bf16x8 af[4], bfr[4];
#pragma unroll
    for (int mi = 0; mi < 4; mi++)
      af[mi] = as_bf(*(const us8*)&As[(wr + mi * 16 + l15) * 32 + quad * 8]);
#pragma unroll
    for (int ni = 0; ni < 4; ni++)
      bfr[ni] = as_bf(*(const us8*)&Bs[(wc + ni * 16 + l15) * 32 + quad * 8]);
#pragma unroll
    for (int mi = 0; mi < 4; mi++)
#pragma unroll
      for (int ni = 0; ni < 4; ni++)
        acc[mi][ni] = __builtin_amdgcn_mfma_f32_16x16x32_bf16(af[mi], bfr[ni], acc[mi][ni], 0, 0, 0);
    __syncthreads();
  }

#pragma unroll
  for (int ni = 0; ni < 4; ni++) {
    const int col = colB0 + wc + ni * 16 + l15;
    float bv = 0.f;
    if constexpr (MODE == MODE_QKV || MODE == MODE_FF1 || MODE == MODE_FF2) bv = bias[col];
#pragma unroll
    for (int mi = 0; mi < 4; mi++) {
      const int row0 = rowA0 + wr + mi * 16 + quad * 4;  // 4 consecutive rows
      if constexpr (MODE == MODE_QKV) {
        unsigned short* o = (unsigned short*)outv;
        if (zidx == 2) {  // V: store transposed per head
          us4 pk;
#pragma unroll
          for (int r = 0; r < 4; r++) pk[r] = f2bf(acc[mi][ni][r] + bv);
          const int bb = row0 >> 11;     // batch (128-row tiles never straddle)
          const int sr = row0 & 2047;    // seq pos
          *(us4*)&o[((size_t)(bb * 1024 + col)) * SEQ + sr] = pk;
        } else {
#pragma unroll
          for (int r = 0; r < 4; r++)
            o[(size_t)(row0 + r) * N + col] = f2bf(acc[mi][ni][r] + bv);
        }
      } else if constexpr (MODE == MODE_FF1) {
        unsigned short* o = (unsigned short*)outv;
#pragma unroll
        for (int r = 0; r < 4; r++) {
          float v = acc[mi][ni][r] + bv;
          v = 0.5f * v * (1.f + erff(v * 0.7071067811865476f));
          o[(size_t)(row0 + r) * N + col] = f2bf(v);
        }
      } else if constexpr (MODE == MODE_PART) {
        unsigned short* o = (unsigned short*)outv;
#pragma unroll
        for (int r = 0; r < 4; r++)
          o[(size_t)(row0 + r) * N + col] = f2bf(acc[mi][ni][r]);
      } else {  // MODE_WO / MODE_FF2 : fp32 out with residual
        float* o = (float*)outv;
#pragma unroll
        for (int r = 0; r < 4; r++) {
          float v = acc[mi][ni][r] + bv + res[(size_t)(row0 + r) * N + col];
          o[(size_t)(row0 + r) * N + col] = v;
        }
      }
    }
  }
}

// ---------------------------------------------------------------------------
// FF2 split-K reduce: out = hb + b2[col] + sum of 4 bf16 partials.
// One thread per 4 consecutive elements (vectorized).
// ---------------------------------------------------------------------------
__global__ __launch_bounds__(256) void ff2_reduce(
    const float* __restrict__ hb, const float* __restrict__ b2,
    const unsigned short* __restrict__ p0, const unsigned short* __restrict__ p1,
    const unsigned short* __restrict__ p2, const unsigned short* __restrict__ p3,
    float* __restrict__ out) {
  const size_t i = ((size_t)blockIdx.x * 256 + threadIdx.x) * 4;
  const int col = (int)(i & (EMBED - 1));
  const float4 h = *(const float4*)&hb[i];
  const float4 bb = *(const float4*)&b2[col];
  const us4 a = *(const us4*)&p0[i];
  const us4 b = *(const us4*)&p1[i];
  const us4 c = *(const us4*)&p2[i];
  const us4 d = *(const us4*)&p3[i];
  float4 o;
  o.x = h.x + bb.x + bf2f(a[0]) + bf2f(b[0]) + bf2f(c[0]) + bf2f(d[0]);
  o.y = h.y + bb.y + bf2f(a[1]) + bf2f(b[1]) + bf2f(c[1]) + bf2f(d[1]);
  o.z = h.z + bb.z + bf2f(a[2]) + bf2f(b[2]) + bf2f(c[2]) + bf2f(d[2]);
  o.w = h.w + bb.w + bf2f(a[3]) + bf2f(b[3]) + bf2f(c[3]) + bf2f(d[3]);
  *(float4*)&out[i] = o;
}

// ---------------------------------------------------------------------------
// Causal flash attention, S^T orientation (see R2 notes).
// ---------------------------------------------------------------------------
__global__ __launch_bounds__(256) void attn_kernel(
    const unsigned short* __restrict__ Q,
    const unsigned short* __restrict__ Kb,
    const unsigned short* __restrict__ Vt,
    unsigned short* __restrict__ Z) {
  __shared__ unsigned short Ksh[2][64][32];  // [d-half][key][32 d]
  __shared__ unsigned short Vsh[2][64][32];  // [key-half][d][32 key]
  __shared__ unsigned short Pt[4][16][72];   // per wave: [q][64 key + pad]
  __shared__ float Ot[4][64][17];            // per wave: [d][16 q + pad]

  const int wave = threadIdx.x >> 6, lane = threadIdx.x & 63;
  const int quad = lane >> 4, l15 = lane & 15;
  const int bh = blockIdx.x, b = bh >> 4, h = bh & 15;
  const int qt = blockIdx.y;
  const int q0 = qt * 128 + wave * 32;
  const float cscale = 1.4426950408889634f / 32.f;  // log2(e)/sqrt(EMBED)

  bf16x8 qf[2][2];
#pragma unroll
  for (int c = 0; c < 2; c++)
#pragma unroll
    for (int kf = 0; kf < 2; kf++)
      qf[c][kf] = as_bf(*(const us8*)&Q[(size_t)(b * SEQ + q0 + c * 16 + l15) * EMBED +
                                        h * 64 + kf * 32 + quad * 8]);

  f32x4 accO[2][4];
#pragma unroll
  for (int c = 0; c < 2; c++)
#pragma unroll
    for (int dt = 0; dt < 4; dt++) accO[c][dt] = f32x4{0.f, 0.f, 0.f, 0.f};
  float mrun[2] = {-INFINITY, -INFINITY};
  float lrun[2] = {0.f, 0.f};

  const int ls_row = lane >> 2;
  const int ls_c16 = lane & 3;
  const int nkt = 2 * qt + 2;

  for (int kt = 0; kt < nkt; kt++) {
    const int kbase = kt * 64;
    const int krow = wave * 16 + ls_row;
#pragma unroll
    for (int kf = 0; kf < 2; kf++) {
      const unsigned short* g =
          &Kb[(size_t)(b * SEQ + kbase + krow) * EMBED + h * 64 + kf * 32 + ls_c16 * 8];
      gload_lds16(g, &Ksh[kf][wave * 16][0] + lane * 8);
    }
#pragma unroll
    for (int kk = 0; kk < 2; kk++) {
      const unsigned short* g =
          &Vt[(size_t)(b * 1024 + h * 64 + krow) * SEQ + kbase + kk * 32 + ls_c16 * 8];
      gload_lds16(g, &Vsh[kk][wave * 16][0] + lane * 8);
    }
    __syncthreads();

#pragma unroll
    for (int c = 0; c < 2; c++) {
      const int qc = q0 + c * 16;
      if (kbase > qc + 15) continue;
      f32x4 sf[4];
#pragma unroll
      for (int nt = 0; nt < 4; nt++) {
        f32x4 z4 = f32x4{0.f, 0.f, 0.f, 0.f};
#pragma unroll
        for (int kf = 0; kf < 2; kf++) {
          const bf16x8 ka = as_bf(*(const us8*)&Ksh[kf][nt * 16 + l15][quad * 8]);
          z4 = __builtin_amdgcn_mfma_f32_16x16x32_bf16(ka, qf[c][kf], z4, 0, 0, 0);
        }
        sf[nt] = z4 * cscale;
      }
      if (kbase + 63 > qc) {
        const int q = qc + l15;
#pragma unroll
        for (int nt = 0; nt < 4; nt++) {
          const int key0 = kbase + nt * 16 + quad * 4;
#pragma unroll
          for (int r = 0; r < 4; r++)
            if (key0 + r > q) sf[nt][r] = -INFINITY;
        }
      }
      float mx = sf[0][0];
#pragma unroll
      for (int nt = 0; nt < 4; nt++)
#pragma unroll
        for (int r = 0; r < 4; r++) mx = fmaxf(mx, sf[nt][r]);
      mx = fmaxf(mx, __shfl_xor(mx, 16, 64));
      mx = fmaxf(mx, __shfl_xor(mx, 32, 64));
      const float mnew = fmaxf(mrun[c], mx);
      const float alpha = exp2f(mrun[c] - mnew);
      mrun[c] = mnew;
      float rs = 0.f;
#pragma unroll
      for (int nt = 0; nt < 4; nt++) {
        us4 pk;
#pragma unroll
        for (int r = 0; r < 4; r++) {
          const float p = exp2f(sf[nt][r] - mnew);
          rs += p;
          pk[r] = f2bf(p);
        }
        *(us4*)&Pt[wave][l15][nt * 16 + quad * 4] = pk;
      }
      rs += __shfl_xor(rs, 16, 64);
      rs += __shfl_xor(rs, 32, 64);
      lrun[c] = lrun[c] * alpha + rs;
#pragma unroll
      for (int dt = 0; dt < 4; dt++) accO[c][dt] = accO[c][dt] * alpha;
      bf16x8 pf[2];
#pragma unroll
      for (int kk = 0; kk < 2; kk++)
        pf[kk] = as_bf(*(const us8*)&Pt[wave][l15][kk * 32 + quad * 8]);
#pragma unroll
      for (int dt = 0; dt < 4; dt++)
#pragma unroll
        for (int kk = 0; kk < 2; kk++) {
          const bf16x8 va = as_bf(*(const us8*)&Vsh[kk][dt * 16 + l15][quad * 8]);
          accO[c][dt] = __builtin_amdgcn_mfma_f32_16x16x32_bf16(va, pf[kk], accO[c][dt], 0, 0, 0);
        }
    }
    __syncthreads();
  }

#pragma unroll
  for (int c = 0; c < 2; c++) {
    const float inv = 1.f / lrun[c];
#pragma unroll
    for (int dt = 0; dt < 4; dt++)
#pragma unroll
      for (int r = 0; r < 4; r++)
        Ot[wave][dt * 16 + quad * 4 + r][l15] = accO[c][dt][r] * inv;
    const int lq = lane >> 2, dbase = (lane & 3) * 16;
    us8 o0, o1;
#pragma unroll
    for (int i = 0; i < 8; i++) o0[i] = f2bf(Ot[wave][dbase + i][lq]);
#pragma unroll
    for (int i = 0; i < 8; i++) o1[i] = f2bf(Ot[wave][dbase + 8 + i][lq]);
    unsigned short* zp = Z + (size_t)(b * SEQ + q0 + c * 16 + lq) * EMBED + h * 64 + dbase;
    *(us8*)zp = o0;
    *(us8*)(zp + 8) = o1;
  }
}

// ---------------------------------------------------------------------------
extern "C" void kernel_launch(void* const* d_in, const int* in_sizes, int n_in,
                              void* d_out, int out_size, void* d_ws, size_t ws_size,
                              hipStream_t stream) {
  const float* x   = (const float*)d_in[0];
  const float* Wq  = (const float*)d_in[1];
  const float* bq  = (const float*)d_in[2];
  const float* Wk  = (const float*)d_in[3];
  const float* bk  = (const float*)d_in[4];
  const float* Wv  = (const float*)d_in[5];
  const float* bv  = (const float*)d_in[6];
  const float* Wo  = (const float*)d_in[7];
  const float* W1  = (const float*)d_in[8];
  const float* b1  = (const float*)d_in[9];
  const float* W2  = (const float*)d_in[10];
  const float* b2  = (const float*)d_in[11];
  const float* g1  = (const float*)d_in[12];
  const float* be1 = (const float*)d_in[13];
  const float* g2  = (const float*)d_in[14];
  const float* be2 = (const float*)d_in[15];
  float* out = (float*)d_out;

  // Workspace map (MB offsets, 88 MB total — same footprint as R1/R2):
  //  0- 2 wqT | 2- 4 wkT | 4- 6 wvT | 6- 8 woT   (dead after QKV / WO)
  //  8-16 w1T (dead after FF1) | 16-24 w2T
  // 24-32 ln1 (dead after QKV) -> zb (dead after WO) -> p2
  // 32-40 qb, 40-48 kb2 (dead after attn) -> hb (fp32, 32-48)
  // 48-56 vT (dead after attn) -> ln2 (dead after FF1) -> p3
  // 56-88 m1
  // p0 = 0-8 (wq..woT dead), p1 = 8-16 (w1T dead)
  char* ws = (char*)d_ws;
  const size_t MB = 1024 * 1024;
  unsigned short* wqT = (unsigned short*)(ws + 0 * MB);
  unsigned short* wkT = (unsigned short*)(ws + 2 * MB);
  unsigned short* wvT = (unsigned short*)(ws + 4 * MB);
  unsigned short* woT = (unsigned short*)(ws + 6 * MB);
  unsigned short* w1T = (unsigned short*)(ws + 8 * MB);
  unsigned short* w2T = (unsigned short*)(ws + 16 * MB);
  unsigned short* ln1 = (unsigned short*)(ws + 24 * MB);
  unsigned short* qb  = (unsigned short*)(ws + 32 * MB);
  unsigned short* kb2 = (unsigned short*)(ws + 40 * MB);
  unsigned short* vT  = (unsigned short*)(ws + 48 * MB);
  unsigned short* zb  = (unsigned short*)(ws + 24 * MB);
  float*          hb  = (float*)         (ws + 32 * MB);
  unsigned short* ln2 = (unsigned short*)(ws + 48 * MB);
  unsigned short* m1  = (unsigned short*)(ws + 56 * MB);
  unsigned short* p0  = (unsigned short*)(ws + 0 * MB);
  unsigned short* p1  = (unsigned short*)(ws + 8 * MB);
  unsigned short* p2  = (unsigned short*)(ws + 24 * MB);
  unsigned short* p3  = (unsigned short*)(ws + 48 * MB);
  (void)in_sizes; (void)n_in; (void)out_size; (void)ws_size;

  transpose_to_bf16<<<dim3(32, 32), 256, 0, stream>>>(Wq, wqT, 1024, 1024);
  transpose_to_bf16<<<dim3(32, 32), 256, 0, stream>>>(Wk, wkT, 1024, 1024);
  transpose_to_bf16<<<dim3(32, 32), 256, 0, stream>>>(Wv, wvT, 1024, 1024);
  transpose_to_bf16<<<dim3(32, 32), 256, 0, stream>>>(Wo, woT, 1024, 1024);
  transpose_to_bf16<<<dim3(128, 32), 256, 0, stream>>>(W1, w1T, 1024, 4096);
  transpose_to_bf16<<<dim3(32, 128), 256, 0, stream>>>(W2, w2T, 4096, 1024);

  layernorm_bf16<<<NROWS / 4, 256, 0, stream>>>(x, g1, be1, ln1);

  gemm_bf16<MODE_QKV><<<dim3(8, 32, 3), 256, 0, stream>>>(
      ln1, wqT, wkT, wvT, bq, bk, bv, nullptr, qb, kb2, vT, nullptr,
      NROWS, 1024, 1024);

  attn_kernel<<<dim3(32, 16), 256, 0, stream>>>(qb, kb2, vT, zb);

  gemm_bf16<MODE_WO><<<dim3(8, 32), 256, 0, stream>>>(
      zb, woT, nullptr, nullptr, nullptr, nullptr, nullptr, x,
      hb, nullptr, nullptr, nullptr, NROWS, 1024, 1024);

  layernorm_bf16<<<NROWS / 4, 256, 0, stream>>>(hb, g2, be2, ln2);

  gemm_bf16<MODE_FF1><<<dim3(32, 32), 256, 0, stream>>>(
      ln2, w1T, nullptr, nullptr, b1, nullptr, nullptr, nullptr,
      m1, nullptr, nullptr, nullptr, NROWS, 4096, 1024);

  // FF2: split-K=4 (grid.z selects K-slice), bf16 partials, then reduce.
  gemm_bf16<MODE_PART><<<dim3(8, 32, 4), 256, 0, stream>>>(
      m1, w2T, nullptr, nullptr, nullptr, nullptr, nullptr, nullptr,
      p0, p1, p2, p3, NROWS, 1024, 4096);

  ff2_reduce<<<NROWS * EMBED / (256 * 4), 256, 0, stream>>>(
      hb, b2, p0, p1, p2, p3, out);
}

// Round 4
// 416.010 us; speedup vs baseline: 1.4459x; 1.0554x over previous
//
#include <hip/hip_runtime.h>
#include <cstdint>
#include <cstddef>
#include <math.h>

#define EMBED 1024
#define SEQ   2048
#define NROWS 4096   // B*S
#define NHEADS 16

typedef __bf16 bf16x8 __attribute__((ext_vector_type(8)));
typedef float f32x4 __attribute__((ext_vector_type(4)));
typedef unsigned short us8 __attribute__((ext_vector_type(8)));
typedef unsigned short us4 __attribute__((ext_vector_type(4)));

__device__ __forceinline__ unsigned short f2bf(float f) {
  union { float f; unsigned u; } v; v.f = f;
  unsigned r = v.u + 0x7fffu + ((v.u >> 16) & 1u);
  return (unsigned short)(r >> 16);
}
__device__ __forceinline__ float bf2f(unsigned short u) {
  union { unsigned u; float f; } v; v.u = (unsigned)u << 16; return v.f;
}

__device__ __forceinline__ bf16x8 as_bf(us8 u) { return __builtin_bit_cast(bf16x8, u); }

__device__ __forceinline__ void gload_lds16(const unsigned short* g, unsigned short* l) {
  __builtin_amdgcn_global_load_lds((const __attribute__((address_space(1))) void*)g,
                                   (__attribute__((address_space(3))) void*)l, 16, 0, 0);
}

// ---------------------------------------------------------------------------
// fp32 [K][N]  ->  bf16 [N][K]   (weight transpose+convert)
// ---------------------------------------------------------------------------
__global__ __launch_bounds__(256) void transpose_to_bf16(
    const float* __restrict__ in, unsigned short* __restrict__ out, int K, int N) {
  __shared__ float tile[32][33];
  const int tx = threadIdx.x & 31, ty = threadIdx.x >> 5;  // 32 x 8
  const int n0 = blockIdx.x * 32, k0 = blockIdx.y * 32;
#pragma unroll
  for (int i = 0; i < 4; i++) {
    int k = ty + i * 8;
    tile[k][tx] = in[(size_t)(k0 + k) * N + n0 + tx];
  }
  __syncthreads();
#pragma unroll
  for (int i = 0; i < 4; i++) {
    int n = ty + i * 8;
    out[(size_t)(n0 + n) * K + k0 + tx] = f2bf(tile[tx][n]);
  }
}

// ---------------------------------------------------------------------------
// LayerNorm: fp32 [rows][1024] -> bf16 [rows][1024].  One wave per row.
// ---------------------------------------------------------------------------
__global__ __launch_bounds__(256) void layernorm_bf16(
    const float* __restrict__ x, const float* __restrict__ g,
    const float* __restrict__ be, unsigned short* __restrict__ out) {
  const int wave = threadIdx.x >> 6, lane = threadIdx.x & 63;
  const int row = blockIdx.x * 4 + wave;
  const float* xr = x + (size_t)row * EMBED;
  float4 v[4];
  float s = 0.f, sq = 0.f;
#pragma unroll
  for (int c = 0; c < 4; c++) {
    v[c] = *(const float4*)&xr[c * 256 + lane * 4];
    s  += v[c].x + v[c].y + v[c].z + v[c].w;
    sq += v[c].x * v[c].x + v[c].y * v[c].y + v[c].z * v[c].z + v[c].w * v[c].w;
  }
#pragma unroll
  for (int m = 1; m < 64; m <<= 1) {
    s  += __shfl_xor(s, m, 64);
    sq += __shfl_xor(sq, m, 64);
  }
  const float mean = s * (1.f / 1024.f);
  const float var  = sq * (1.f / 1024.f) - mean * mean;
  const float rstd = rsqrtf(var + 1e-5f);
#pragma unroll
  for (int c = 0; c < 4; c++) {
    const int idx = c * 256 + lane * 4;
    us4 o;
    o[0] = f2bf((v[c].x - mean) * rstd * g[idx + 0] + be[idx + 0]);
    o[1] = f2bf((v[c].y - mean) * rstd * g[idx + 1] + be[idx + 1]);
    o[2] = f2bf((v[c].z - mean) * rstd * g[idx + 2] + be[idx + 2]);
    o[3] = f2bf((v[c].w - mean) * rstd * g[idx + 3] + be[idx + 3]);
    *(us4*)&out[(size_t)row * EMBED + idx] = o;
  }
}

// ---------------------------------------------------------------------------
// Fused LN2: h = x + pw0 + pw1 (WO split-K partials); writes h (fp32) and
// layernorm(h) (bf16).  One wave per row.
// ---------------------------------------------------------------------------
__global__ __launch_bounds__(256) void ln2_fused(
    const float* __restrict__ x,
    const unsigned short* __restrict__ pw0,
    const unsigned short* __restrict__ pw1,
    const float* __restrict__ g, const float* __restrict__ be,
    float* __restrict__ hb, unsigned short* __restrict__ out) {
  const int wave = threadIdx.x >> 6, lane = threadIdx.x & 63;
  const int row = blockIdx.x * 4 + wave;
  const size_t rb = (size_t)row * EMBED;
  float4 v[4];
  float s = 0.f, sq = 0.f;
#pragma unroll
  for (int c = 0; c < 4; c++) {
    const int idx = c * 256 + lane * 4;
    const float4 xv = *(const float4*)&x[rb + idx];
    const us4 a = *(const us4*)&pw0[rb + idx];
    const us4 d = *(const us4*)&pw1[rb + idx];
    v[c].x = xv.x + bf2f(a[0]) + bf2f(d[0]);
    v[c].y = xv.y + bf2f(a[1]) + bf2f(d[1]);
    v[c].z = xv.z + bf2f(a[2]) + bf2f(d[2]);
    v[c].w = xv.w + bf2f(a[3]) + bf2f(d[3]);
    *(float4*)&hb[rb + idx] = v[c];
    s  += v[c].x + v[c].y + v[c].z + v[c].w;
    sq += v[c].x * v[c].x + v[c].y * v[c].y + v[c].z * v[c].z + v[c].w * v[c].w;
  }
#pragma unroll
  for (int m = 1; m < 64; m <<= 1) {
    s  += __shfl_xor(s, m, 64);
    sq += __shfl_xor(sq, m, 64);
  }
  const float mean = s * (1.f / 1024.f);
  const float var  = sq * (1.f / 1024.f) - mean * mean;
  const float rstd = rsqrtf(var + 1e-5f);
#pragma unroll
  for (int c = 0; c < 4; c++) {
    const int idx = c * 256 + lane * 4;
    us4 o;
    o[0] = f2bf((v[c].x - mean) * rstd * g[idx + 0] + be[idx + 0]);
    o[1] = f2bf((v[c].y - mean) * rstd * g[idx + 1] + be[idx + 1]);
    o[2] = f2bf((v[c].z - mean) * rstd * g[idx + 2] + be[idx + 2]);
    o[3] = f2bf((v[c].w - mean) * rstd * g[idx + 3] + be[idx + 3]);
    *(us4*)&out[rb + idx] = o;
  }
}

// ---------------------------------------------------------------------------
// bf16 GEMM, m97 structure: C[M,N] = A[M,K] @ Bt[N,K]^T, 128x128 tile, BK=32.
// MODE_PART: split-K — gridDim.z slices of K/gridDim.z; stores raw acc bf16.
// ---------------------------------------------------------------------------
enum { MODE_QKV = 0, MODE_WO = 1, MODE_FF1 = 2, MODE_FF2 = 3, MODE_PART = 4 };

template <int MODE>
__global__ __launch_bounds__(256) void gemm_bf16(
    const unsigned short* __restrict__ A,
    const unsigned short* __restrict__ Bt0,
    const unsigned short* __restrict__ Bt1,
    const unsigned short* __restrict__ Bt2,
    const float* __restrict__ bias0,
    const float* __restrict__ bias1,
    const float* __restrict__ bias2,
    const float* __restrict__ res,
    void* __restrict__ out0, void* __restrict__ out1,
    void* __restrict__ out2, void* __restrict__ out3,
    int M, int N, int K) {
  const unsigned short* Bt = Bt0;
  const float* bias = bias0;
  void* outv = out0;
  int zidx = 0;
  if constexpr (MODE == MODE_QKV) {
    zidx = blockIdx.z;
    if (zidx == 1)      { Bt = Bt1; bias = bias1; outv = out1; }
    else if (zidx == 2) { Bt = Bt2; bias = bias2; outv = out2; }
  }
  if constexpr (MODE == MODE_PART) {
    zidx = blockIdx.z;
    outv = (zidx == 0) ? out0 : (zidx == 1) ? out1 : (zidx == 2) ? out2 : out3;
  }
  const int Ksub = (MODE == MODE_PART) ? K / (int)gridDim.z : K;
  const int koff = (MODE == MODE_PART) ? zidx * Ksub : 0;

  __shared__ unsigned short As[128 * 32];
  __shared__ unsigned short Bs[128 * 32];
  const int tid = threadIdx.x;
  const int wave = tid >> 6, lane = tid & 63;
  const int quad = lane >> 4, l15 = lane & 15;
  const int wr = (wave >> 1) * 64, wc = (wave & 1) * 64;
  const int rowA0 = blockIdx.y * 128, colB0 = blockIdx.x * 128;

  const int srow = tid >> 2;
  const int scol = (tid & 3) * 8;
  const unsigned short* gA = A  + (size_t)(rowA0 + srow) * K + koff + scol;
  const unsigned short* gB = Bt + (size_t)(colB0 + srow) * K + koff + scol;
  unsigned short* lA  = &As[tid * 8];
  unsigned short* lA2 = &As[2048 + tid * 8];
  unsigned short* lB  = &Bs[tid * 8];
  unsigned short* lB2 = &Bs[2048 + tid * 8];
  const size_t half = (size_t)64 * K;

  f32x4 acc[4][4];
#pragma unroll
  for (int i = 0; i < 4; i++)
#pragma unroll
    for (int j = 0; j < 4; j++) acc[i][j] = f32x4{0.f, 0.f, 0.f, 0.f};

  for (int k0 = 0; k0 < Ksub; k0 += 32) {
    gload_lds16(gA + k0, lA);
    gload_lds16(gA + half + k0, lA2);
    gload_lds16(gB + k0, lB);
    gload_lds16(gB + half + k0, lB2);
    __syncthreads();
    bf16x8 af[4], bfr[4];
#pragma unroll
    for (int mi = 0; mi < 4; mi++)
      af[mi] = as_bf(*(const us8*)&As[(wr + mi * 16 + l15) * 32 + quad * 8]);
#pragma unroll
    for (int ni = 0; ni < 4; ni++)
      bfr[ni] = as_bf(*(const us8*)&Bs[(wc + ni * 16 + l15) * 32 + quad * 8]);
#pragma unroll
    for (int mi = 0; mi < 4; mi++)
#pragma unroll
      for (int ni = 0; ni < 4; ni++)
        acc[mi][ni] = __builtin_amdgcn_mfma_f32_16x16x32_bf16(af[mi], bfr[ni], acc[mi][ni], 0, 0, 0);
    __syncthreads();
  }

#pragma unroll
  for (int ni = 0; ni < 4; ni++) {
    const int col = colB0 + wc + ni * 16 + l15;
    float bv = 0.f;
    if constexpr (MODE == MODE_QKV || MODE == MODE_FF1 || MODE == MODE_FF2) bv = bias[col];
#pragma unroll
    for (int mi = 0; mi < 4; mi++) {
      const int row0 = rowA0 + wr + mi * 16 + quad * 4;  // 4 consecutive rows
      if constexpr (MODE == MODE_QKV) {
        unsigned short* o = (unsigned short*)outv;
        if (zidx == 2) {  // V: store transposed per head
          us4 pk;
#pragma unroll
          for (int r = 0; r < 4; r++) pk[r] = f2bf(acc[mi][ni][r] + bv);
          const int bb = row0 >> 11;     // batch (128-row tiles never straddle)
          const int sr = row0 & 2047;    // seq pos
          *(us4*)&o[((size_t)(bb * 1024 + col)) * SEQ + sr] = pk;
        } else {
#pragma unroll
          for (int r = 0; r < 4; r++)
            o[(size_t)(row0 + r) * N + col] = f2bf(acc[mi][ni][r] + bv);
        }
      } else if constexpr (MODE == MODE_FF1) {
        unsigned short* o = (unsigned short*)outv;
#pragma unroll
        for (int r = 0; r < 4; r++) {
          float v = acc[mi][ni][r] + bv;
          v = 0.5f * v * (1.f + erff(v * 0.7071067811865476f));
          o[(size_t)(row0 + r) * N + col] = f2bf(v);
        }
      } else if constexpr (MODE == MODE_PART) {
        unsigned short* o = (unsigned short*)outv;
#pragma unroll
        for (int r = 0; r < 4; r++)
          o[(size_t)(row0 + r) * N + col] = f2bf(acc[mi][ni][r]);
      } else {  // MODE_WO / MODE_FF2 : fp32 out with residual
        float* o = (float*)outv;
#pragma unroll
        for (int r = 0; r < 4; r++) {
          float v = acc[mi][ni][r] + bv + res[(size_t)(row0 + r) * N + col];
          o[(size_t)(row0 + r) * N + col] = v;
        }
      }
    }
  }
}

// ---------------------------------------------------------------------------
// FF2 split-K reduce: out = hb + b2[col] + sum of 4 bf16 partials.
// ---------------------------------------------------------------------------
__global__ __launch_bounds__(256) void ff2_reduce(
    const float* __restrict__ hb, const float* __restrict__ b2,
    const unsigned short* __restrict__ p0, const unsigned short* __restrict__ p1,
    const unsigned short* __restrict__ p2, const unsigned short* __restrict__ p3,
    float* __restrict__ out) {
  const size_t i = ((size_t)blockIdx.x * 256 + threadIdx.x) * 4;
  const int col = (int)(i & (EMBED - 1));
  const float4 h = *(const float4*)&hb[i];
  const float4 bb = *(const float4*)&b2[col];
  const us4 a = *(const us4*)&p0[i];
  const us4 b = *(const us4*)&p1[i];
  const us4 c = *(const us4*)&p2[i];
  const us4 d = *(const us4*)&p3[i];
  float4 o;
  o.x = h.x + bb.x + bf2f(a[0]) + bf2f(b[0]) + bf2f(c[0]) + bf2f(d[0]);
  o.y = h.y + bb.y + bf2f(a[1]) + bf2f(b[1]) + bf2f(c[1]) + bf2f(d[1]);
  o.z = h.z + bb.z + bf2f(a[2]) + bf2f(b[2]) + bf2f(c[2]) + bf2f(d[2]);
  o.w = h.w + bb.w + bf2f(a[3]) + bf2f(b[3]) + bf2f(c[3]) + bf2f(d[3]);
  *(float4*)&out[i] = o;
}

// ---------------------------------------------------------------------------
// Causal flash attention, S^T orientation, balanced + conflict-free.
// grid (bh=32, pair=16).  Block handles q-tiles j=pair and j=31-pair (64 rows
// each) -> constant 33 k-tiles per block (perfect balance, 512 blocks = 2/CU).
// Wave w owns 16 q rows of the current tile.  K/V tiles staged to LDS with
// 72-short (144 B) padded rows via VGPR round-trip: fragment ds_read_b128
// banks = (4*l15 + c) mod 32 -> 2-way = free (was 8-way with 64 B rows).
// ---------------------------------------------------------------------------
__global__ __launch_bounds__(256) void attn_kernel(
    const unsigned short* __restrict__ Q,
    const unsigned short* __restrict__ Kb,
    const unsigned short* __restrict__ Vt,
    unsigned short* __restrict__ Z) {
  __shared__ unsigned short Ksh[64][72];   // [key][64 d + pad]
  __shared__ unsigned short Vsh[64][72];   // [d][64 key + pad]
  __shared__ unsigned short Pt[4][16][72]; // per wave: [q][64 key + pad]
  __shared__ float Ot[4][64][17];          // per wave: [d][16 q + pad]

  const int tid = threadIdx.x;
  const int wave = tid >> 6, lane = tid & 63;
  const int quad = lane >> 4, l15 = lane & 15;
  const int bh = blockIdx.x, b = bh >> 4, h = bh & 15;
  const float cscale = 1.4426950408889634f / 32.f;  // log2(e)/sqrt(EMBED)

  const int srow = tid >> 2;       // 0..63 staging row
  const int sc = (tid & 3) * 8;    // staging col offset (shorts)
  const unsigned short* Kbase = Kb + (size_t)(b * SEQ) * EMBED + h * 64;
  const unsigned short* Vbase = Vt + (size_t)(b * 1024 + h * 64) * SEQ;

#pragma unroll
  for (int ph = 0; ph < 2; ph++) {
    const int j = ph ? 31 - (int)blockIdx.y : (int)blockIdx.y;  // q-tile (64 rows)
    const int qc = j * 64 + wave * 16;                          // this wave's 16 rows

    bf16x8 qf[2];
#pragma unroll
    for (int kf = 0; kf < 2; kf++)
      qf[kf] = as_bf(*(const us8*)&Q[(size_t)(b * SEQ + qc + l15) * EMBED +
                                     h * 64 + kf * 32 + quad * 8]);

    f32x4 accO[4];
#pragma unroll
    for (int dt = 0; dt < 4; dt++) accO[dt] = f32x4{0.f, 0.f, 0.f, 0.f};
    float mrun = -INFINITY, lrun = 0.f;

    for (int kt = 0; kt <= j; kt++) {
      const int kbase = kt * 64;
      // issue staging loads early (latency overlaps the barrier)
      const unsigned short* kg = Kbase + (size_t)(kbase + srow) * EMBED + sc;
      const unsigned short* vg = Vbase + (size_t)srow * SEQ + kbase + sc;
      const us8 k0 = *(const us8*)kg;
      const us8 k1 = *(const us8*)(kg + 32);
      const us8 v0 = *(const us8*)vg;
      const us8 v1 = *(const us8*)(vg + 32);
      __syncthreads();  // previous tile's consumers done
      *(us8*)&Ksh[srow][sc]      = k0;
      *(us8*)&Ksh[srow][32 + sc] = k1;
      *(us8*)&Vsh[srow][sc]      = v0;
      *(us8*)&Vsh[srow][32 + sc] = v1;
      __syncthreads();  // tile visible

      // ---- S^T = K · Q^T ----
      f32x4 sf[4];
#pragma unroll
      for (int nt = 0; nt < 4; nt++) {
        f32x4 z4 = f32x4{0.f, 0.f, 0.f, 0.f};
#pragma unroll
        for (int kf = 0; kf < 2; kf++) {
          const bf16x8 ka = as_bf(*(const us8*)&Ksh[nt * 16 + l15][kf * 32 + quad * 8]);
          z4 = __builtin_amdgcn_mfma_f32_16x16x32_bf16(ka, qf[kf], z4, 0, 0, 0);
        }
        sf[nt] = z4 * cscale;
      }
      // ---- causal mask (diagonal tile only) ----
      if (kt == j) {
        const int q = qc + l15;
#pragma unroll
        for (int nt = 0; nt < 4; nt++) {
          const int key0 = kbase + nt * 16 + quad * 4;
#pragma unroll
          for (int r = 0; r < 4; r++)
            if (key0 + r > q) sf[nt][r] = -INFINITY;
        }
      }
      // ---- online softmax (stats per q = per lane) ----
      float mx = sf[0][0];
#pragma unroll
      for (int nt = 0; nt < 4; nt++)
#pragma unroll
        for (int r = 0; r < 4; r++) mx = fmaxf(mx, sf[nt][r]);
      mx = fmaxf(mx, __shfl_xor(mx, 16, 64));
      mx = fmaxf(mx, __shfl_xor(mx, 32, 64));
      const float mnew = fmaxf(mrun, mx);
      const float alpha = exp2f(mrun - mnew);
      mrun = mnew;
      float rs = 0.f;
#pragma unroll
      for (int nt = 0; nt < 4; nt++) {
        us4 pk;
#pragma unroll
        for (int r = 0; r < 4; r++) {
          const float p = exp2f(sf[nt][r] - mnew);
          rs += p;
          pk[r] = f2bf(p);
        }
        *(us4*)&Pt[wave][l15][nt * 16 + quad * 4] = pk;
      }
      rs += __shfl_xor(rs, 16, 64);
      rs += __shfl_xor(rs, 32, 64);
      lrun = lrun * alpha + rs;
#pragma unroll
      for (int dt = 0; dt < 4; dt++) accO[dt] = accO[dt] * alpha;
      // ---- O^T += V^T · P^T ----
      bf16x8 pf[2];
#pragma unroll
      for (int kk = 0; kk < 2; kk++)
        pf[kk] = as_bf(*(const us8*)&Pt[wave][l15][kk * 32 + quad * 8]);
#pragma unroll
      for (int dt = 0; dt < 4; dt++)
#pragma unroll
        for (int kk = 0; kk < 2; kk++) {
          const bf16x8 va = as_bf(*(const us8*)&Vsh[dt * 16 + l15][kk * 32 + quad * 8]);
          accO[dt] = __builtin_amdgcn_mfma_f32_16x16x32_bf16(va, pf[kk], accO[dt], 0, 0, 0);
        }
    }

    // ---- epilogue: /l, transpose O^T -> O via per-wave LDS, store bf16 ----
    const float inv = 1.f / lrun;
#pragma unroll
    for (int dt = 0; dt < 4; dt++)
#pragma unroll
      for (int r = 0; r < 4; r++)
        Ot[wave][dt * 16 + quad * 4 + r][l15] = accO[dt][r] * inv;
    const int lq = lane >> 2, dbase = (lane & 3) * 16;
    us8 o0, o1;
#pragma unroll
    for (int i = 0; i < 8; i++) o0[i] = f2bf(Ot[wave][dbase + i][lq]);
#pragma unroll
    for (int i = 0; i < 8; i++) o1[i] = f2bf(Ot[wave][dbase + 8 + i][lq]);
    unsigned short* zp = Z + (size_t)(b * SEQ + qc + lq) * EMBED + h * 64 + dbase;
    *(us8*)zp = o0;
    *(us8*)(zp + 8) = o1;
  }
}

// ---------------------------------------------------------------------------
extern "C" void kernel_launch(void* const* d_in, const int* in_sizes, int n_in,
                              void* d_out, int out_size, void* d_ws, size_t ws_size,
                              hipStream_t stream) {
  const float* x   = (const float*)d_in[0];
  const float* Wq  = (const float*)d_in[1];
  const float* bq  = (const float*)d_in[2];
  const float* Wk  = (const float*)d_in[3];
  const float* bk  = (const float*)d_in[4];
  const float* Wv  = (const float*)d_in[5];
  const float* bv  = (const float*)d_in[6];
  const float* Wo  = (const float*)d_in[7];
  const float* W1  = (const float*)d_in[8];
  const float* b1  = (const float*)d_in[9];
  const float* W2  = (const float*)d_in[10];
  const float* b2  = (const float*)d_in[11];
  const float* g1  = (const float*)d_in[12];
  const float* be1 = (const float*)d_in[13];
  const float* g2  = (const float*)d_in[14];
  const float* be2 = (const float*)d_in[15];
  float* out = (float*)d_out;

  // Workspace map (MB offsets, 88 MB total):
  //  0- 8: wqT/wkT/wvT/woT  -> p0 (FF2 partial)
  //  8-16: w1T              -> p1
  // 16-24: w2T (live until FF2)
  // 24-32: ln1 -> zb (attn out) -> ln2 -> p2
  // 32-48: qb(32-40) + kb2(40-48) -> hb (fp32, after attn)
  // 48-56: vT -> pw0 (WO partial) -> p3
  // 56-88: m1 (56-64 doubles as pw1 before FF1)
  char* ws = (char*)d_ws;
  const size_t MB = 1024 * 1024;
  unsigned short* wqT = (unsigned short*)(ws + 0 * MB);
  unsigned short* wkT = (unsigned short*)(ws + 2 * MB);
  unsigned short* wvT = (unsigned short*)(ws + 4 * MB);
  unsigned short* woT = (unsigned short*)(ws + 6 * MB);
  unsigned short* w1T = (unsigned short*)(ws + 8 * MB);
  unsigned short* w2T = (unsigned short*)(ws + 16 * MB);
  unsigned short* ln1 = (unsigned short*)(ws + 24 * MB);
  unsigned short* zb  = (unsigned short*)(ws + 24 * MB);
  unsigned short* ln2 = (unsigned short*)(ws + 24 * MB);
  unsigned short* p2  = (unsigned short*)(ws + 24 * MB);
  unsigned short* qb  = (unsigned short*)(ws + 32 * MB);
  unsigned short* kb2 = (unsigned short*)(ws + 40 * MB);
  float*          hb  = (float*)         (ws + 32 * MB);
  unsigned short* vT  = (unsigned short*)(ws + 48 * MB);
  unsigned short* pw0 = (unsigned short*)(ws + 48 * MB);
  unsigned short* p3  = (unsigned short*)(ws + 48 * MB);
  unsigned short* pw1 = (unsigned short*)(ws + 56 * MB);
  unsigned short* m1  = (unsigned short*)(ws + 56 * MB);
  unsigned short* p0  = (unsigned short*)(ws + 0 * MB);
  unsigned short* p1  = (unsigned short*)(ws + 8 * MB);
  (void)in_sizes; (void)n_in; (void)out_size; (void)ws_size;

  transpose_to_bf16<<<dim3(32, 32), 256, 0, stream>>>(Wq, wqT, 1024, 1024);
  transpose_to_bf16<<<dim3(32, 32), 256, 0, stream>>>(Wk, wkT, 1024, 1024);
  transpose_to_bf16<<<dim3(32, 32), 256, 0, stream>>>(Wv, wvT, 1024, 1024);
  transpose_to_bf16<<<dim3(32, 32), 256, 0, stream>>>(Wo, woT, 1024, 1024);
  transpose_to_bf16<<<dim3(128, 32), 256, 0, stream>>>(W1, w1T, 1024, 4096);
  transpose_to_bf16<<<dim3(32, 128), 256, 0, stream>>>(W2, w2T, 4096, 1024);

  layernorm_bf16<<<NROWS / 4, 256, 0, stream>>>(x, g1, be1, ln1);

  gemm_bf16<MODE_QKV><<<dim3(8, 32, 3), 256, 0, stream>>>(
      ln1, wqT, wkT, wvT, bq, bk, bv, nullptr, qb, kb2, vT, nullptr,
      NROWS, 1024, 1024);

  attn_kernel<<<dim3(32, 16), 256, 0, stream>>>(qb, kb2, vT, zb);

  // WO: split-K=2, bf16 partials; residual + LN fused into ln2_fused.
  gemm_bf16<MODE_PART><<<dim3(8, 32, 2), 256, 0, stream>>>(
      zb, woT, nullptr, nullptr, nullptr, nullptr, nullptr, nullptr,
      pw0, pw1, nullptr, nullptr, NROWS, 1024, 1024);

  ln2_fused<<<NROWS / 4, 256, 0, stream>>>(x, pw0, pw1, g2, be2, hb, ln2);

  gemm_bf16<MODE_FF1><<<dim3(32, 32), 256, 0, stream>>>(
      ln2, w1T, nullptr, nullptr, b1, nullptr, nullptr, nullptr,
      m1, nullptr, nullptr, nullptr, NROWS, 4096, 1024);

  // FF2: split-K=4, bf16 partials, then reduce.
  gemm_bf16<MODE_PART><<<dim3(8, 32, 4), 256, 0, stream>>>(
      m1, w2T, nullptr, nullptr, nullptr, nullptr, nullptr, nullptr,
      p0, p1, p2, p3, NROWS, 1024, 4096);

  ff2_reduce<<<NROWS * EMBED / (256 * 4), 256, 0, stream>>>(
      hb, b2, p0, p1, p2, p3, out);
}

// Round 5
// 389.155 us; speedup vs baseline: 1.5457x; 1.0690x over previous
//
#include <hip/hip_runtime.h>
#include <cstdint>
#include <cstddef>
#include <math.h>

#define EMBED 1024
#define SEQ   2048
#define NROWS 4096   // B*S
#define NHEADS 16

typedef __bf16 bf16x8 __attribute__((ext_vector_type(8)));
typedef float f32x4 __attribute__((ext_vector_type(4)));
typedef unsigned short us8 __attribute__((ext_vector_type(8)));
typedef unsigned short us4 __attribute__((ext_vector_type(4)));

__device__ __forceinline__ unsigned short f2bf(float f) {
  union { float f; unsigned u; } v; v.f = f;
  unsigned r = v.u + 0x7fffu + ((v.u >> 16) & 1u);
  return (unsigned short)(r >> 16);
}
__device__ __forceinline__ float bf2f(unsigned short u) {
  union { unsigned u; float f; } v; v.u = (unsigned)u << 16; return v.f;
}

__device__ __forceinline__ bf16x8 as_bf(us8 u) { return __builtin_bit_cast(bf16x8, u); }

// ---------------------------------------------------------------------------
// fp32 [K][N]  ->  bf16 [N][K]   (weight transpose+convert)
// ---------------------------------------------------------------------------
__global__ __launch_bounds__(256) void transpose_to_bf16(
    const float* __restrict__ in, unsigned short* __restrict__ out, int K, int N) {
  __shared__ float tile[32][33];
  const int tx = threadIdx.x & 31, ty = threadIdx.x >> 5;  // 32 x 8
  const int n0 = blockIdx.x * 32, k0 = blockIdx.y * 32;
#pragma unroll
  for (int i = 0; i < 4; i++) {
    int k = ty + i * 8;
    tile[k][tx] = in[(size_t)(k0 + k) * N + n0 + tx];
  }
  __syncthreads();
#pragma unroll
  for (int i = 0; i < 4; i++) {
    int n = ty + i * 8;
    out[(size_t)(n0 + n) * K + k0 + tx] = f2bf(tile[tx][n]);
  }
}

// ---------------------------------------------------------------------------
// LayerNorm: fp32 [rows][1024] -> bf16 [rows][1024].  One wave per row.
// ---------------------------------------------------------------------------
__global__ __launch_bounds__(256) void layernorm_bf16(
    const float* __restrict__ x, const float* __restrict__ g,
    const float* __restrict__ be, unsigned short* __restrict__ out) {
  const int wave = threadIdx.x >> 6, lane = threadIdx.x & 63;
  const int row = blockIdx.x * 4 + wave;
  const float* xr = x + (size_t)row * EMBED;
  float4 v[4];
  float s = 0.f, sq = 0.f;
#pragma unroll
  for (int c = 0; c < 4; c++) {
    v[c] = *(const float4*)&xr[c * 256 + lane * 4];
    s  += v[c].x + v[c].y + v[c].z + v[c].w;
    sq += v[c].x * v[c].x + v[c].y * v[c].y + v[c].z * v[c].z + v[c].w * v[c].w;
  }
#pragma unroll
  for (int m = 1; m < 64; m <<= 1) {
    s  += __shfl_xor(s, m, 64);
    sq += __shfl_xor(sq, m, 64);
  }
  const float mean = s * (1.f / 1024.f);
  const float var  = sq * (1.f / 1024.f) - mean * mean;
  const float rstd = rsqrtf(var + 1e-5f);
#pragma unroll
  for (int c = 0; c < 4; c++) {
    const int idx = c * 256 + lane * 4;
    us4 o;
    o[0] = f2bf((v[c].x - mean) * rstd * g[idx + 0] + be[idx + 0]);
    o[1] = f2bf((v[c].y - mean) * rstd * g[idx + 1] + be[idx + 1]);
    o[2] = f2bf((v[c].z - mean) * rstd * g[idx + 2] + be[idx + 2]);
    o[3] = f2bf((v[c].w - mean) * rstd * g[idx + 3] + be[idx + 3]);
    *(us4*)&out[(size_t)row * EMBED + idx] = o;
  }
}

// ---------------------------------------------------------------------------
// Fused LN2: h = x + pw0 + pw1 (WO split-K partials); writes h (fp32) and
// layernorm(h) (bf16).  One wave per row.
// ---------------------------------------------------------------------------
__global__ __launch_bounds__(256) void ln2_fused(
    const float* __restrict__ x,
    const unsigned short* __restrict__ pw0,
    const unsigned short* __restrict__ pw1,
    const float* __restrict__ g, const float* __restrict__ be,
    float* __restrict__ hb, unsigned short* __restrict__ out) {
  const int wave = threadIdx.x >> 6, lane = threadIdx.x & 63;
  const int row = blockIdx.x * 4 + wave;
  const size_t rb = (size_t)row * EMBED;
  float4 v[4];
  float s = 0.f, sq = 0.f;
#pragma unroll
  for (int c = 0; c < 4; c++) {
    const int idx = c * 256 + lane * 4;
    const float4 xv = *(const float4*)&x[rb + idx];
    const us4 a = *(const us4*)&pw0[rb + idx];
    const us4 d = *(const us4*)&pw1[rb + idx];
    v[c].x = xv.x + bf2f(a[0]) + bf2f(d[0]);
    v[c].y = xv.y + bf2f(a[1]) + bf2f(d[1]);
    v[c].z = xv.z + bf2f(a[2]) + bf2f(d[2]);
    v[c].w = xv.w + bf2f(a[3]) + bf2f(d[3]);
    *(float4*)&hb[rb + idx] = v[c];
    s  += v[c].x + v[c].y + v[c].z + v[c].w;
    sq += v[c].x * v[c].x + v[c].y * v[c].y + v[c].z * v[c].z + v[c].w * v[c].w;
  }
#pragma unroll
  for (int m = 1; m < 64; m <<= 1) {
    s  += __shfl_xor(s, m, 64);
    sq += __shfl_xor(sq, m, 64);
  }
  const float mean = s * (1.f / 1024.f);
  const float var  = sq * (1.f / 1024.f) - mean * mean;
  const float rstd = rsqrtf(var + 1e-5f);
#pragma unroll
  for (int c = 0; c < 4; c++) {
    const int idx = c * 256 + lane * 4;
    us4 o;
    o[0] = f2bf((v[c].x - mean) * rstd * g[idx + 0] + be[idx + 0]);
    o[1] = f2bf((v[c].y - mean) * rstd * g[idx + 1] + be[idx + 1]);
    o[2] = f2bf((v[c].z - mean) * rstd * g[idx + 2] + be[idx + 2]);
    o[3] = f2bf((v[c].w - mean) * rstd * g[idx + 3] + be[idx + 3]);
    *(us4*)&out[rb + idx] = o;
  }
}

// ---------------------------------------------------------------------------
// bf16 GEMM: C[M,N] = A[M,K] @ Bt[N,K]^T, 128x128 tile, BK=32.
// R5: register-prefetch pipeline + padded LDS (36-short rows, conflict-free).
// Per k-iter: [barrier; ds_write tile k from regs; issue global loads k+1;
// barrier; ds_read frags + 16 MFMA].  The vmcnt wait for the prefetch lands
// after a full compute phase instead of inside the barrier pair.
// MODE_PART: split-K — gridDim.z slices of K/gridDim.z; stores raw acc bf16.
// ---------------------------------------------------------------------------
enum { MODE_QKV = 0, MODE_WO = 1, MODE_FF1 = 2, MODE_FF2 = 3, MODE_PART = 4 };

#define LDW 36  // padded LDS row width (shorts): start dword = 18*row+4*chunk
                // mod 32 -> 16 distinct even residues -> b128 2-way = free

template <int MODE>
__global__ __launch_bounds__(256) void gemm_bf16(
    const unsigned short* __restrict__ A,
    const unsigned short* __restrict__ Bt0,
    const unsigned short* __restrict__ Bt1,
    const unsigned short* __restrict__ Bt2,
    const float* __restrict__ bias0,
    const float* __restrict__ bias1,
    const float* __restrict__ bias2,
    const float* __restrict__ res,
    void* __restrict__ out0, void* __restrict__ out1,
    void* __restrict__ out2, void* __restrict__ out3,
    int M, int N, int K) {
  const unsigned short* Bt = Bt0;
  const float* bias = bias0;
  void* outv = out0;
  int zidx = 0;
  if constexpr (MODE == MODE_QKV) {
    zidx = blockIdx.z;
    if (zidx == 1)      { Bt = Bt1; bias = bias1; outv = out1; }
    else if (zidx == 2) { Bt = Bt2; bias = bias2; outv = out2; }
  }
  if constexpr (MODE == MODE_PART) {
    zidx = blockIdx.z;
    outv = (zidx == 0) ? out0 : (zidx == 1) ? out1 : (zidx == 2) ? out2 : out3;
  }
  const int Ksub = (MODE == MODE_PART) ? K / (int)gridDim.z : K;
  const int koff = (MODE == MODE_PART) ? zidx * Ksub : 0;

  __shared__ unsigned short As[128 * LDW];
  __shared__ unsigned short Bs[128 * LDW];
  const int tid = threadIdx.x;
  const int wave = tid >> 6, lane = tid & 63;
  const int quad = lane >> 4, l15 = lane & 15;
  const int wr = (wave >> 1) * 64, wc = (wave & 1) * 64;
  const int rowA0 = blockIdx.y * 128, colB0 = blockIdx.x * 128;

  const int srow = tid >> 2;        // 0..63 (rows srow and srow+64)
  const int scol = (tid & 3) * 8;   // 16B chunk within 64B row slice
  const unsigned short* gA = A  + (size_t)(rowA0 + srow) * K + koff + scol;
  const unsigned short* gB = Bt + (size_t)(colB0 + srow) * K + koff + scol;
  const size_t half = (size_t)64 * K;

  // prologue: prefetch tile 0 into registers
  us8 ra0 = *(const us8*)gA;
  us8 ra1 = *(const us8*)(gA + half);
  us8 rb0 = *(const us8*)gB;
  us8 rb1 = *(const us8*)(gB + half);

  f32x4 acc[4][4];
#pragma unroll
  for (int i = 0; i < 4; i++)
#pragma unroll
    for (int j = 0; j < 4; j++) acc[i][j] = f32x4{0.f, 0.f, 0.f, 0.f};

  for (int k0 = 0; k0 < Ksub; k0 += 32) {
    __syncthreads();  // previous iter's LDS consumers done
    *(us8*)&As[srow * LDW + scol]        = ra0;
    *(us8*)&As[(srow + 64) * LDW + scol] = ra1;
    *(us8*)&Bs[srow * LDW + scol]        = rb0;
    *(us8*)&Bs[(srow + 64) * LDW + scol] = rb1;
    if (k0 + 32 < Ksub) {  // issue prefetch for k+1 (consumed next iter)
      ra0 = *(const us8*)(gA + k0 + 32);
      ra1 = *(const us8*)(gA + half + k0 + 32);
      rb0 = *(const us8*)(gB + k0 + 32);
      rb1 = *(const us8*)(gB + half + k0 + 32);
    }
    __syncthreads();  // tile k visible
    bf16x8 af[4], bfr[4];
#pragma unroll
    for (int mi = 0; mi < 4; mi++)
      af[mi] = as_bf(*(const us8*)&As[(wr + mi * 16 + l15) * LDW + quad * 8]);
#pragma unroll
    for (int ni = 0; ni < 4; ni++)
      bfr[ni] = as_bf(*(const us8*)&Bs[(wc + ni * 16 + l15) * LDW + quad * 8]);
#pragma unroll
    for (int mi = 0; mi < 4; mi++)
#pragma unroll
      for (int ni = 0; ni < 4; ni++)
        acc[mi][ni] = __builtin_amdgcn_mfma_f32_16x16x32_bf16(af[mi], bfr[ni], acc[mi][ni], 0, 0, 0);
  }

#pragma unroll
  for (int ni = 0; ni < 4; ni++) {
    const int col = colB0 + wc + ni * 16 + l15;
    float bv = 0.f;
    if constexpr (MODE == MODE_QKV || MODE == MODE_FF1 || MODE == MODE_FF2) bv = bias[col];
#pragma unroll
    for (int mi = 0; mi < 4; mi++) {
      const int row0 = rowA0 + wr + mi * 16 + quad * 4;  // 4 consecutive rows
      if constexpr (MODE == MODE_QKV) {
        unsigned short* o = (unsigned short*)outv;
        if (zidx == 2) {  // V: store transposed per head
          us4 pk;
#pragma unroll
          for (int r = 0; r < 4; r++) pk[r] = f2bf(acc[mi][ni][r] + bv);
          const int bb = row0 >> 11;     // batch (128-row tiles never straddle)
          const int sr = row0 & 2047;    // seq pos
          *(us4*)&o[((size_t)(bb * 1024 + col)) * SEQ + sr] = pk;
        } else {
#pragma unroll
          for (int r = 0; r < 4; r++)
            o[(size_t)(row0 + r) * N + col] = f2bf(acc[mi][ni][r] + bv);
        }
      } else if constexpr (MODE == MODE_FF1) {
        unsigned short* o = (unsigned short*)outv;
#pragma unroll
        for (int r = 0; r < 4; r++) {
          float v = acc[mi][ni][r] + bv;
          v = 0.5f * v * (1.f + erff(v * 0.7071067811865476f));
          o[(size_t)(row0 + r) * N + col] = f2bf(v);
        }
      } else if constexpr (MODE == MODE_PART) {
        unsigned short* o = (unsigned short*)outv;
#pragma unroll
        for (int r = 0; r < 4; r++)
          o[(size_t)(row0 + r) * N + col] = f2bf(acc[mi][ni][r]);
      } else {  // MODE_WO / MODE_FF2 : fp32 out with residual
        float* o = (float*)outv;
#pragma unroll
        for (int r = 0; r < 4; r++) {
          float v = acc[mi][ni][r] + bv + res[(size_t)(row0 + r) * N + col];
          o[(size_t)(row0 + r) * N + col] = v;
        }
      }
    }
  }
}

// ---------------------------------------------------------------------------
// FF2 split-K reduce: out = hb + b2[col] + sum of 4 bf16 partials.
// ---------------------------------------------------------------------------
__global__ __launch_bounds__(256) void ff2_reduce(
    const float* __restrict__ hb, const float* __restrict__ b2,
    const unsigned short* __restrict__ p0, const unsigned short* __restrict__ p1,
    const unsigned short* __restrict__ p2, const unsigned short* __restrict__ p3,
    float* __restrict__ out) {
  const size_t i = ((size_t)blockIdx.x * 256 + threadIdx.x) * 4;
  const int col = (int)(i & (EMBED - 1));
  const float4 h = *(const float4*)&hb[i];
  const float4 bb = *(const float4*)&b2[col];
  const us4 a = *(const us4*)&p0[i];
  const us4 b = *(const us4*)&p1[i];
  const us4 c = *(const us4*)&p2[i];
  const us4 d = *(const us4*)&p3[i];
  float4 o;
  o.x = h.x + bb.x + bf2f(a[0]) + bf2f(b[0]) + bf2f(c[0]) + bf2f(d[0]);
  o.y = h.y + bb.y + bf2f(a[1]) + bf2f(b[1]) + bf2f(c[1]) + bf2f(d[1]);
  o.z = h.z + bb.z + bf2f(a[2]) + bf2f(b[2]) + bf2f(c[2]) + bf2f(d[2]);
  o.w = h.w + bb.w + bf2f(a[3]) + bf2f(b[3]) + bf2f(c[3]) + bf2f(d[3]);
  *(float4*)&out[i] = o;
}

// ---------------------------------------------------------------------------
// Causal flash attention, S^T orientation, balanced + conflict-free (R4).
// ---------------------------------------------------------------------------
__global__ __launch_bounds__(256) void attn_kernel(
    const unsigned short* __restrict__ Q,
    const unsigned short* __restrict__ Kb,
    const unsigned short* __restrict__ Vt,
    unsigned short* __restrict__ Z) {
  __shared__ unsigned short Ksh[64][72];   // [key][64 d + pad]
  __shared__ unsigned short Vsh[64][72];   // [d][64 key + pad]
  __shared__ unsigned short Pt[4][16][72]; // per wave: [q][64 key + pad]
  __shared__ float Ot[4][64][17];          // per wave: [d][16 q + pad]

  const int tid = threadIdx.x;
  const int wave = tid >> 6, lane = tid & 63;
  const int quad = lane >> 4, l15 = lane & 15;
  const int bh = blockIdx.x, b = bh >> 4, h = bh & 15;
  const float cscale = 1.4426950408889634f / 32.f;  // log2(e)/sqrt(EMBED)

  const int srow = tid >> 2;       // 0..63 staging row
  const int sc = (tid & 3) * 8;    // staging col offset (shorts)
  const unsigned short* Kbase = Kb + (size_t)(b * SEQ) * EMBED + h * 64;
  const unsigned short* Vbase = Vt + (size_t)(b * 1024 + h * 64) * SEQ;

#pragma unroll
  for (int ph = 0; ph < 2; ph++) {
    const int j = ph ? 31 - (int)blockIdx.y : (int)blockIdx.y;  // q-tile (64 rows)
    const int qc = j * 64 + wave * 16;                          // this wave's 16 rows

    bf16x8 qf[2];
#pragma unroll
    for (int kf = 0; kf < 2; kf++)
      qf[kf] = as_bf(*(const us8*)&Q[(size_t)(b * SEQ + qc + l15) * EMBED +
                                     h * 64 + kf * 32 + quad * 8]);

    f32x4 accO[4];
#pragma unroll
    for (int dt = 0; dt < 4; dt++) accO[dt] = f32x4{0.f, 0.f, 0.f, 0.f};
    float mrun = -INFINITY, lrun = 0.f;

    for (int kt = 0; kt <= j; kt++) {
      const int kbase = kt * 64;
      const unsigned short* kg = Kbase + (size_t)(kbase + srow) * EMBED + sc;
      const unsigned short* vg = Vbase + (size_t)srow * SEQ + kbase + sc;
      const us8 k0 = *(const us8*)kg;
      const us8 k1 = *(const us8*)(kg + 32);
      const us8 v0 = *(const us8*)vg;
      const us8 v1 = *(const us8*)(vg + 32);
      __syncthreads();
      *(us8*)&Ksh[srow][sc]      = k0;
      *(us8*)&Ksh[srow][32 + sc] = k1;
      *(us8*)&Vsh[srow][sc]      = v0;
      *(us8*)&Vsh[srow][32 + sc] = v1;
      __syncthreads();

      f32x4 sf[4];
#pragma unroll
      for (int nt = 0; nt < 4; nt++) {
        f32x4 z4 = f32x4{0.f, 0.f, 0.f, 0.f};
#pragma unroll
        for (int kf = 0; kf < 2; kf++) {
          const bf16x8 ka = as_bf(*(const us8*)&Ksh[nt * 16 + l15][kf * 32 + quad * 8]);
          z4 = __builtin_amdgcn_mfma_f32_16x16x32_bf16(ka, qf[kf], z4, 0, 0, 0);
        }
        sf[nt] = z4 * cscale;
      }
      if (kt == j) {
        const int q = qc + l15;
#pragma unroll
        for (int nt = 0; nt < 4; nt++) {
          const int key0 = kbase + nt * 16 + quad * 4;
#pragma unroll
          for (int r = 0; r < 4; r++)
            if (key0 + r > q) sf[nt][r] = -INFINITY;
        }
      }
      float mx = sf[0][0];
#pragma unroll
      for (int nt = 0; nt < 4; nt++)
#pragma unroll
        for (int r = 0; r < 4; r++) mx = fmaxf(mx, sf[nt][r]);
      mx = fmaxf(mx, __shfl_xor(mx, 16, 64));
      mx = fmaxf(mx, __shfl_xor(mx, 32, 64));
      const float mnew = fmaxf(mrun, mx);
      const float alpha = exp2f(mrun - mnew);
      mrun = mnew;
      float rs = 0.f;
#pragma unroll
      for (int nt = 0; nt < 4; nt++) {
        us4 pk;
#pragma unroll
        for (int r = 0; r < 4; r++) {
          const float p = exp2f(sf[nt][r] - mnew);
          rs += p;
          pk[r] = f2bf(p);
        }
        *(us4*)&Pt[wave][l15][nt * 16 + quad * 4] = pk;
      }
      rs += __shfl_xor(rs, 16, 64);
      rs += __shfl_xor(rs, 32, 64);
      lrun = lrun * alpha + rs;
#pragma unroll
      for (int dt = 0; dt < 4; dt++) accO[dt] = accO[dt] * alpha;
      bf16x8 pf[2];
#pragma unroll
      for (int kk = 0; kk < 2; kk++)
        pf[kk] = as_bf(*(const us8*)&Pt[wave][l15][kk * 32 + quad * 8]);
#pragma unroll
      for (int dt = 0; dt < 4; dt++)
#pragma unroll
        for (int kk = 0; kk < 2; kk++) {
          const bf16x8 va = as_bf(*(const us8*)&Vsh[dt * 16 + l15][kk * 32 + quad * 8]);
          accO[dt] = __builtin_amdgcn_mfma_f32_16x16x32_bf16(va, pf[kk], accO[dt], 0, 0, 0);
        }
    }

    const float inv = 1.f / lrun;
#pragma unroll
    for (int dt = 0; dt < 4; dt++)
#pragma unroll
      for (int r = 0; r < 4; r++)
        Ot[wave][dt * 16 + quad * 4 + r][l15] = accO[dt][r] * inv;
    const int lq = lane >> 2, dbase = (lane & 3) * 16;
    us8 o0, o1;
#pragma unroll
    for (int i = 0; i < 8; i++) o0[i] = f2bf(Ot[wave][dbase + i][lq]);
#pragma unroll
    for (int i = 0; i < 8; i++) o1[i] = f2bf(Ot[wave][dbase + 8 + i][lq]);
    unsigned short* zp = Z + (size_t)(b * SEQ + qc + lq) * EMBED + h * 64 + dbase;
    *(us8*)zp = o0;
    *(us8*)(zp + 8) = o1;
  }
}

// ---------------------------------------------------------------------------
extern "C" void kernel_launch(void* const* d_in, const int* in_sizes, int n_in,
                              void* d_out, int out_size, void* d_ws, size_t ws_size,
                              hipStream_t stream) {
  const float* x   = (const float*)d_in[0];
  const float* Wq  = (const float*)d_in[1];
  const float* bq  = (const float*)d_in[2];
  const float* Wk  = (const float*)d_in[3];
  const float* bk  = (const float*)d_in[4];
  const float* Wv  = (const float*)d_in[5];
  const float* bv  = (const float*)d_in[6];
  const float* Wo  = (const float*)d_in[7];
  const float* W1  = (const float*)d_in[8];
  const float* b1  = (const float*)d_in[9];
  const float* W2  = (const float*)d_in[10];
  const float* b2  = (const float*)d_in[11];
  const float* g1  = (const float*)d_in[12];
  const float* be1 = (const float*)d_in[13];
  const float* g2  = (const float*)d_in[14];
  const float* be2 = (const float*)d_in[15];
  float* out = (float*)d_out;

  // Workspace map (MB offsets, 88 MB total):
  //  0- 8: wqT/wkT/wvT/woT  -> p0 (FF2 partial)
  //  8-16: w1T              -> p1
  // 16-24: w2T (live until FF2)
  // 24-32: ln1 -> zb (attn out) -> ln2 -> p2
  // 32-48: qb(32-40) + kb2(40-48) -> hb (fp32, after attn)
  // 48-56: vT -> pw0 (WO partial) -> p3
  // 56-88: m1 (56-64 doubles as pw1 before FF1)
  char* ws = (char*)d_ws;
  const size_t MB = 1024 * 1024;
  unsigned short* wqT = (unsigned short*)(ws + 0 * MB);
  unsigned short* wkT = (unsigned short*)(ws + 2 * MB);
  unsigned short* wvT = (unsigned short*)(ws + 4 * MB);
  unsigned short* woT = (unsigned short*)(ws + 6 * MB);
  unsigned short* w1T = (unsigned short*)(ws + 8 * MB);
  unsigned short* w2T = (unsigned short*)(ws + 16 * MB);
  unsigned short* ln1 = (unsigned short*)(ws + 24 * MB);
  unsigned short* zb  = (unsigned short*)(ws + 24 * MB);
  unsigned short* ln2 = (unsigned short*)(ws + 24 * MB);
  unsigned short* p2  = (unsigned short*)(ws + 24 * MB);
  unsigned short* qb  = (unsigned short*)(ws + 32 * MB);
  unsigned short* kb2 = (unsigned short*)(ws + 40 * MB);
  float*          hb  = (float*)         (ws + 32 * MB);
  unsigned short* vT  = (unsigned short*)(ws + 48 * MB);
  unsigned short* pw0 = (unsigned short*)(ws + 48 * MB);
  unsigned short* p3  = (unsigned short*)(ws + 48 * MB);
  unsigned short* pw1 = (unsigned short*)(ws + 56 * MB);
  unsigned short* m1  = (unsigned short*)(ws + 56 * MB);
  unsigned short* p0  = (unsigned short*)(ws + 0 * MB);
  unsigned short* p1  = (unsigned short*)(ws + 8 * MB);
  (void)in_sizes; (void)n_in; (void)out_size; (void)ws_size;

  transpose_to_bf16<<<dim3(32, 32), 256, 0, stream>>>(Wq, wqT, 1024, 1024);
  transpose_to_bf16<<<dim3(32, 32), 256, 0, stream>>>(Wk, wkT, 1024, 1024);
  transpose_to_bf16<<<dim3(32, 32), 256, 0, stream>>>(Wv, wvT, 1024, 1024);
  transpose_to_bf16<<<dim3(32, 32), 256, 0, stream>>>(Wo, woT, 1024, 1024);
  transpose_to_bf16<<<dim3(128, 32), 256, 0, stream>>>(W1, w1T, 1024, 4096);
  transpose_to_bf16<<<dim3(32, 128), 256, 0, stream>>>(W2, w2T, 4096, 1024);

  layernorm_bf16<<<NROWS / 4, 256, 0, stream>>>(x, g1, be1, ln1);

  gemm_bf16<MODE_QKV><<<dim3(8, 32, 3), 256, 0, stream>>>(
      ln1, wqT, wkT, wvT, bq, bk, bv, nullptr, qb, kb2, vT, nullptr,
      NROWS, 1024, 1024);

  attn_kernel<<<dim3(32, 16), 256, 0, stream>>>(qb, kb2, vT, zb);

  // WO: split-K=2, bf16 partials; residual + LN fused into ln2_fused.
  gemm_bf16<MODE_PART><<<dim3(8, 32, 2), 256, 0, stream>>>(
      zb, woT, nullptr, nullptr, nullptr, nullptr, nullptr, nullptr,
      pw0, pw1, nullptr, nullptr, NROWS, 1024, 1024);

  ln2_fused<<<NROWS / 4, 256, 0, stream>>>(x, pw0, pw1, g2, be2, hb, ln2);

  gemm_bf16<MODE_FF1><<<dim3(32, 32), 256, 0, stream>>>(
      ln2, w1T, nullptr, nullptr, b1, nullptr, nullptr, nullptr,
      m1, nullptr, nullptr, nullptr, NROWS, 4096, 1024);

  // FF2: split-K=4, bf16 partials, then reduce.
  gemm_bf16<MODE_PART><<<dim3(8, 32, 4), 256, 0, stream>>>(
      m1, w2T, nullptr, nullptr, nullptr, nullptr, nullptr, nullptr,
      p0, p1, p2, p3, NROWS, 1024, 4096);

  ff2_reduce<<<NROWS * EMBED / (256 * 4), 256, 0, stream>>>(
      hb, b2, p0, p1, p2, p3, out);
}

// Round 6
// 378.982 us; speedup vs baseline: 1.5872x; 1.0268x over previous
//
#include <hip/hip_runtime.h>
#include <cstdint>
#include <cstddef>
#include <math.h>

#define EMBED 1024
#define SEQ   2048
#define NROWS 4096   // B*S
#define NHEADS 16

typedef __bf16 bf16x8 __attribute__((ext_vector_type(8)));
typedef float f32x4 __attribute__((ext_vector_type(4)));
typedef unsigned short us8 __attribute__((ext_vector_type(8)));
typedef unsigned short us4 __attribute__((ext_vector_type(4)));

__device__ __forceinline__ unsigned short f2bf(float f) {
  union { float f; unsigned u; } v; v.f = f;
  unsigned r = v.u + 0x7fffu + ((v.u >> 16) & 1u);
  return (unsigned short)(r >> 16);
}
__device__ __forceinline__ float bf2f(unsigned short u) {
  union { unsigned u; float f; } v; v.u = (unsigned)u << 16; return v.f;
}

__device__ __forceinline__ bf16x8 as_bf(us8 u) { return __builtin_bit_cast(bf16x8, u); }

// ---------------------------------------------------------------------------
// All six weight transposes (fp32 [K][N] -> bf16 [N][K]) in ONE launch.
// Segments: [0,4096) four 1024x1024 weights; [4096,8192) W1 (1024x4096);
// [8192,12288) W2 (4096x1024).
// ---------------------------------------------------------------------------
__global__ __launch_bounds__(256) void transpose_all(
    const float* __restrict__ Wq, const float* __restrict__ Wk,
    const float* __restrict__ Wv, const float* __restrict__ Wo,
    const float* __restrict__ W1, const float* __restrict__ W2,
    unsigned short* __restrict__ wqT, unsigned short* __restrict__ wkT,
    unsigned short* __restrict__ wvT, unsigned short* __restrict__ woT,
    unsigned short* __restrict__ w1T, unsigned short* __restrict__ w2T) {
  __shared__ float tile[32][33];
  const int bid = blockIdx.x;
  const float* in;
  unsigned short* out;
  int K, N, bx, by;
  if (bid < 4096) {
    const int w = bid >> 10, t = bid & 1023;
    in  = (w == 0) ? Wq  : (w == 1) ? Wk  : (w == 2) ? Wv  : Wo;
    out = (w == 0) ? wqT : (w == 1) ? wkT : (w == 2) ? wvT : woT;
    K = 1024; N = 1024; bx = t & 31; by = t >> 5;
  } else if (bid < 8192) {
    const int t = bid - 4096;
    in = W1; out = w1T; K = 1024; N = 4096; bx = t & 127; by = t >> 7;
  } else {
    const int t = bid - 8192;
    in = W2; out = w2T; K = 4096; N = 1024; bx = t & 31; by = t >> 5;
  }
  const int tx = threadIdx.x & 31, ty = threadIdx.x >> 5;  // 32 x 8
  const int n0 = bx * 32, k0 = by * 32;
#pragma unroll
  for (int i = 0; i < 4; i++) {
    int k = ty + i * 8;
    tile[k][tx] = in[(size_t)(k0 + k) * N + n0 + tx];
  }
  __syncthreads();
#pragma unroll
  for (int i = 0; i < 4; i++) {
    int n = ty + i * 8;
    out[(size_t)(n0 + n) * K + k0 + tx] = f2bf(tile[tx][n]);
  }
}

// ---------------------------------------------------------------------------
// LayerNorm: fp32 [rows][1024] -> bf16 [rows][1024].  One wave per row.
// ---------------------------------------------------------------------------
__global__ __launch_bounds__(256) void layernorm_bf16(
    const float* __restrict__ x, const float* __restrict__ g,
    const float* __restrict__ be, unsigned short* __restrict__ out) {
  const int wave = threadIdx.x >> 6, lane = threadIdx.x & 63;
  const int row = blockIdx.x * 4 + wave;
  const float* xr = x + (size_t)row * EMBED;
  float4 v[4];
  float s = 0.f, sq = 0.f;
#pragma unroll
  for (int c = 0; c < 4; c++) {
    v[c] = *(const float4*)&xr[c * 256 + lane * 4];
    s  += v[c].x + v[c].y + v[c].z + v[c].w;
    sq += v[c].x * v[c].x + v[c].y * v[c].y + v[c].z * v[c].z + v[c].w * v[c].w;
  }
#pragma unroll
  for (int m = 1; m < 64; m <<= 1) {
    s  += __shfl_xor(s, m, 64);
    sq += __shfl_xor(sq, m, 64);
  }
  const float mean = s * (1.f / 1024.f);
  const float var  = sq * (1.f / 1024.f) - mean * mean;
  const float rstd = rsqrtf(var + 1e-5f);
#pragma unroll
  for (int c = 0; c < 4; c++) {
    const int idx = c * 256 + lane * 4;
    us4 o;
    o[0] = f2bf((v[c].x - mean) * rstd * g[idx + 0] + be[idx + 0]);
    o[1] = f2bf((v[c].y - mean) * rstd * g[idx + 1] + be[idx + 1]);
    o[2] = f2bf((v[c].z - mean) * rstd * g[idx + 2] + be[idx + 2]);
    o[3] = f2bf((v[c].w - mean) * rstd * g[idx + 3] + be[idx + 3]);
    *(us4*)&out[(size_t)row * EMBED + idx] = o;
  }
}

// ---------------------------------------------------------------------------
// Fused LN2: h = x + pw0 + pw1 (WO split-K partials); writes h (fp32) and
// layernorm(h) (bf16).  One wave per row.
// ---------------------------------------------------------------------------
__global__ __launch_bounds__(256) void ln2_fused(
    const float* __restrict__ x,
    const unsigned short* __restrict__ pw0,
    const unsigned short* __restrict__ pw1,
    const float* __restrict__ g, const float* __restrict__ be,
    float* __restrict__ hb, unsigned short* __restrict__ out) {
  const int wave = threadIdx.x >> 6, lane = threadIdx.x & 63;
  const int row = blockIdx.x * 4 + wave;
  const size_t rb = (size_t)row * EMBED;
  float4 v[4];
  float s = 0.f, sq = 0.f;
#pragma unroll
  for (int c = 0; c < 4; c++) {
    const int idx = c * 256 + lane * 4;
    const float4 xv = *(const float4*)&x[rb + idx];
    const us4 a = *(const us4*)&pw0[rb + idx];
    const us4 d = *(const us4*)&pw1[rb + idx];
    v[c].x = xv.x + bf2f(a[0]) + bf2f(d[0]);
    v[c].y = xv.y + bf2f(a[1]) + bf2f(d[1]);
    v[c].z = xv.z + bf2f(a[2]) + bf2f(d[2]);
    v[c].w = xv.w + bf2f(a[3]) + bf2f(d[3]);
    *(float4*)&hb[rb + idx] = v[c];
    s  += v[c].x + v[c].y + v[c].z + v[c].w;
    sq += v[c].x * v[c].x + v[c].y * v[c].y + v[c].z * v[c].z + v[c].w * v[c].w;
  }
#pragma unroll
  for (int m = 1; m < 64; m <<= 1) {
    s  += __shfl_xor(s, m, 64);
    sq += __shfl_xor(sq, m, 64);
  }
  const float mean = s * (1.f / 1024.f);
  const float var  = sq * (1.f / 1024.f) - mean * mean;
  const float rstd = rsqrtf(var + 1e-5f);
#pragma unroll
  for (int c = 0; c < 4; c++) {
    const int idx = c * 256 + lane * 4;
    us4 o;
    o[0] = f2bf((v[c].x - mean) * rstd * g[idx + 0] + be[idx + 0]);
    o[1] = f2bf((v[c].y - mean) * rstd * g[idx + 1] + be[idx + 1]);
    o[2] = f2bf((v[c].z - mean) * rstd * g[idx + 2] + be[idx + 2]);
    o[3] = f2bf((v[c].w - mean) * rstd * g[idx + 3] + be[idx + 3]);
    *(us4*)&out[rb + idx] = o;
  }
}

// ---------------------------------------------------------------------------
// bf16 GEMM: C[M,N] = A[M,K] @ Bt[N,K]^T, 128x128 tile, BK=32.
// R6: double-buffered LDS + 3-slot register prefetch, ONE barrier per k-iter.
// Iter k: ds_write tile k+1 -> buf^1 (prev barrier protects), issue global
// loads for tile k+3 (12 outstanding -> partial vmcnt waits, ~2-iter window),
// compute tile k from buf, barrier.  NITER is a template param so the loop
// fully unrolls with static register-slot indices.
// ---------------------------------------------------------------------------
enum { MODE_QKV = 0, MODE_WO = 1, MODE_FF1 = 2, MODE_FF2 = 3, MODE_PART = 4 };

#define LDW 36  // padded LDS row width (shorts) — conflict-light b128 access

template <int MODE, int NITER>
__global__ __launch_bounds__(256) void gemm_bf16(
    const unsigned short* __restrict__ A,
    const unsigned short* __restrict__ Bt0,
    const unsigned short* __restrict__ Bt1,
    const unsigned short* __restrict__ Bt2,
    const float* __restrict__ bias0,
    const float* __restrict__ bias1,
    const float* __restrict__ bias2,
    const float* __restrict__ res,
    void* __restrict__ out0, void* __restrict__ out1,
    void* __restrict__ out2, void* __restrict__ out3,
    int M, int N, int K) {
  const unsigned short* Bt = Bt0;
  const float* bias = bias0;
  void* outv = out0;
  int zidx = 0;
  if constexpr (MODE == MODE_QKV) {
    zidx = blockIdx.z;
    if (zidx == 1)      { Bt = Bt1; bias = bias1; outv = out1; }
    else if (zidx == 2) { Bt = Bt2; bias = bias2; outv = out2; }
  }
  if constexpr (MODE == MODE_PART) {
    zidx = blockIdx.z;
    outv = (zidx == 0) ? out0 : (zidx == 1) ? out1 : (zidx == 2) ? out2 : out3;
  }
  const int koff = (MODE == MODE_PART) ? zidx * (NITER * 32) : 0;

  __shared__ unsigned short As[2][128 * LDW];
  __shared__ unsigned short Bs[2][128 * LDW];
  const int tid = threadIdx.x;
  const int wave = tid >> 6, lane = tid & 63;
  const int quad = lane >> 4, l15 = lane & 15;
  const int wr = (wave >> 1) * 64, wc = (wave & 1) * 64;
  const int rowA0 = blockIdx.y * 128, colB0 = blockIdx.x * 128;

  const int srow = tid >> 2;        // 0..63 (rows srow and srow+64)
  const int scol = (tid & 3) * 8;   // 16B chunk within 64B row slice
  const unsigned short* gA = A  + (size_t)(rowA0 + srow) * K + koff + scol;
  const unsigned short* gB = Bt + (size_t)(colB0 + srow) * K + koff + scol;
  const size_t half = (size_t)64 * K;

  // 3 register prefetch slots; slot for tile t is t % 3.
  us8 pa0[3], pa1[3], pb0[3], pb1[3];
#pragma unroll
  for (int s = 0; s < 3; s++) {
    if (s < NITER) {
      pa0[s] = *(const us8*)(gA + s * 32);
      pa1[s] = *(const us8*)(gA + half + s * 32);
      pb0[s] = *(const us8*)(gB + s * 32);
      pb1[s] = *(const us8*)(gB + half + s * 32);
    }
  }
  // stage tile 0 into buf 0 (waits only slot-0 loads)
  *(us8*)&As[0][srow * LDW + scol]        = pa0[0];
  *(us8*)&As[0][(srow + 64) * LDW + scol] = pa1[0];
  *(us8*)&Bs[0][srow * LDW + scol]        = pb0[0];
  *(us8*)&Bs[0][(srow + 64) * LDW + scol] = pb1[0];
  __syncthreads();

  f32x4 acc[4][4];
#pragma unroll
  for (int i = 0; i < 4; i++)
#pragma unroll
    for (int j = 0; j < 4; j++) acc[i][j] = f32x4{0.f, 0.f, 0.f, 0.f};

#pragma unroll
  for (int k = 0; k < NITER; k++) {
    const int buf = k & 1;
    if (k + 1 < NITER) {  // stage tile k+1 into the other buffer
      const int s = (k + 1) % 3;
      *(us8*)&As[buf ^ 1][srow * LDW + scol]        = pa0[s];
      *(us8*)&As[buf ^ 1][(srow + 64) * LDW + scol] = pa1[s];
      *(us8*)&Bs[buf ^ 1][srow * LDW + scol]        = pb0[s];
      *(us8*)&Bs[buf ^ 1][(srow + 64) * LDW + scol] = pb1[s];
    }
    if (k + 3 < NITER) {  // issue loads for tile k+3 (slot freed by the write above)
      const int s = k % 3;
      pa0[s] = *(const us8*)(gA + (size_t)(k + 3) * 32);
      pa1[s] = *(const us8*)(gA + half + (size_t)(k + 3) * 32);
      pb0[s] = *(const us8*)(gB + (size_t)(k + 3) * 32);
      pb1[s] = *(const us8*)(gB + half + (size_t)(k + 3) * 32);
    }
    bf16x8 af[4], bfr[4];
#pragma unroll
    for (int mi = 0; mi < 4; mi++)
      af[mi] = as_bf(*(const us8*)&As[buf][(wr + mi * 16 + l15) * LDW + quad * 8]);
#pragma unroll
    for (int ni = 0; ni < 4; ni++)
      bfr[ni] = as_bf(*(const us8*)&Bs[buf][(wc + ni * 16 + l15) * LDW + quad * 8]);
#pragma unroll
    for (int mi = 0; mi < 4; mi++)
#pragma unroll
      for (int ni = 0; ni < 4; ni++)
        acc[mi][ni] = __builtin_amdgcn_mfma_f32_16x16x32_bf16(af[mi], bfr[ni], acc[mi][ni], 0, 0, 0);
    if (k + 1 < NITER) __syncthreads();
  }

#pragma unroll
  for (int ni = 0; ni < 4; ni++) {
    const int col = colB0 + wc + ni * 16 + l15;
    float bv = 0.f;
    if constexpr (MODE == MODE_QKV || MODE == MODE_FF1 || MODE == MODE_FF2) bv = bias[col];
#pragma unroll
    for (int mi = 0; mi < 4; mi++) {
      const int row0 = rowA0 + wr + mi * 16 + quad * 4;  // 4 consecutive rows
      if constexpr (MODE == MODE_QKV) {
        unsigned short* o = (unsigned short*)outv;
        if (zidx == 2) {  // V: store transposed per head
          us4 pk;
#pragma unroll
          for (int r = 0; r < 4; r++) pk[r] = f2bf(acc[mi][ni][r] + bv);
          const int bb = row0 >> 11;     // batch (128-row tiles never straddle)
          const int sr = row0 & 2047;    // seq pos
          *(us4*)&o[((size_t)(bb * 1024 + col)) * SEQ + sr] = pk;
        } else {
#pragma unroll
          for (int r = 0; r < 4; r++)
            o[(size_t)(row0 + r) * N + col] = f2bf(acc[mi][ni][r] + bv);
        }
      } else if constexpr (MODE == MODE_FF1) {
        unsigned short* o = (unsigned short*)outv;
#pragma unroll
        for (int r = 0; r < 4; r++) {
          float v = acc[mi][ni][r] + bv;
          v = 0.5f * v * (1.f + erff(v * 0.7071067811865476f));
          o[(size_t)(row0 + r) * N + col] = f2bf(v);
        }
      } else if constexpr (MODE == MODE_PART) {
        unsigned short* o = (unsigned short*)outv;
#pragma unroll
        for (int r = 0; r < 4; r++)
          o[(size_t)(row0 + r) * N + col] = f2bf(acc[mi][ni][r]);
      } else {  // MODE_WO / MODE_FF2 : fp32 out with residual
        float* o = (float*)outv;
#pragma unroll
        for (int r = 0; r < 4; r++) {
          float v = acc[mi][ni][r] + bv + res[(size_t)(row0 + r) * N + col];
          o[(size_t)(row0 + r) * N + col] = v;
        }
      }
    }
  }
}

// ---------------------------------------------------------------------------
// FF2 split-K reduce: out = hb + b2[col] + sum of 4 bf16 partials.
// ---------------------------------------------------------------------------
__global__ __launch_bounds__(256) void ff2_reduce(
    const float* __restrict__ hb, const float* __restrict__ b2,
    const unsigned short* __restrict__ p0, const unsigned short* __restrict__ p1,
    const unsigned short* __restrict__ p2, const unsigned short* __restrict__ p3,
    float* __restrict__ out) {
  const size_t i = ((size_t)blockIdx.x * 256 + threadIdx.x) * 4;
  const int col = (int)(i & (EMBED - 1));
  const float4 h = *(const float4*)&hb[i];
  const float4 bb = *(const float4*)&b2[col];
  const us4 a = *(const us4*)&p0[i];
  const us4 b = *(const us4*)&p1[i];
  const us4 c = *(const us4*)&p2[i];
  const us4 d = *(const us4*)&p3[i];
  float4 o;
  o.x = h.x + bb.x + bf2f(a[0]) + bf2f(b[0]) + bf2f(c[0]) + bf2f(d[0]);
  o.y = h.y + bb.y + bf2f(a[1]) + bf2f(b[1]) + bf2f(c[1]) + bf2f(d[1]);
  o.z = h.z + bb.z + bf2f(a[2]) + bf2f(b[2]) + bf2f(c[2]) + bf2f(d[2]);
  o.w = h.w + bb.w + bf2f(a[3]) + bf2f(b[3]) + bf2f(c[3]) + bf2f(d[3]);
  *(float4*)&out[i] = o;
}

// ---------------------------------------------------------------------------
// Causal flash attention, S^T orientation, balanced + conflict-free (R4).
// ---------------------------------------------------------------------------
__global__ __launch_bounds__(256) void attn_kernel(
    const unsigned short* __restrict__ Q,
    const unsigned short* __restrict__ Kb,
    const unsigned short* __restrict__ Vt,
    unsigned short* __restrict__ Z) {
  __shared__ unsigned short Ksh[64][72];   // [key][64 d + pad]
  __shared__ unsigned short Vsh[64][72];   // [d][64 key + pad]
  __shared__ unsigned short Pt[4][16][72]; // per wave: [q][64 key + pad]
  __shared__ float Ot[4][64][17];          // per wave: [d][16 q + pad]

  const int tid = threadIdx.x;
  const int wave = tid >> 6, lane = tid & 63;
  const int quad = lane >> 4, l15 = lane & 15;
  const int bh = blockIdx.x, b = bh >> 4, h = bh & 15;
  const float cscale = 1.4426950408889634f / 32.f;  // log2(e)/sqrt(EMBED)

  const int srow = tid >> 2;       // 0..63 staging row
  const int sc = (tid & 3) * 8;    // staging col offset (shorts)
  const unsigned short* Kbase = Kb + (size_t)(b * SEQ) * EMBED + h * 64;
  const unsigned short* Vbase = Vt + (size_t)(b * 1024 + h * 64) * SEQ;

#pragma unroll
  for (int ph = 0; ph < 2; ph++) {
    const int j = ph ? 31 - (int)blockIdx.y : (int)blockIdx.y;  // q-tile (64 rows)
    const int qc = j * 64 + wave * 16;                          // this wave's 16 rows

    bf16x8 qf[2];
#pragma unroll
    for (int kf = 0; kf < 2; kf++)
      qf[kf] = as_bf(*(const us8*)&Q[(size_t)(b * SEQ + qc + l15) * EMBED +
                                     h * 64 + kf * 32 + quad * 8]);

    f32x4 accO[4];
#pragma unroll
    for (int dt = 0; dt < 4; dt++) accO[dt] = f32x4{0.f, 0.f, 0.f, 0.f};
    float mrun = -INFINITY, lrun = 0.f;

    for (int kt = 0; kt <= j; kt++) {
      const int kbase = kt * 64;
      const unsigned short* kg = Kbase + (size_t)(kbase + srow) * EMBED + sc;
      const unsigned short* vg = Vbase + (size_t)srow * SEQ + kbase + sc;
      const us8 k0 = *(const us8*)kg;
      const us8 k1 = *(const us8*)(kg + 32);
      const us8 v0 = *(const us8*)vg;
      const us8 v1 = *(const us8*)(vg + 32);
      __syncthreads();
      *(us8*)&Ksh[srow][sc]      = k0;
      *(us8*)&Ksh[srow][32 + sc] = k1;
      *(us8*)&Vsh[srow][sc]      = v0;
      *(us8*)&Vsh[srow][32 + sc] = v1;
      __syncthreads();

      f32x4 sf[4];
#pragma unroll
      for (int nt = 0; nt < 4; nt++) {
        f32x4 z4 = f32x4{0.f, 0.f, 0.f, 0.f};
#pragma unroll
        for (int kf = 0; kf < 2; kf++) {
          const bf16x8 ka = as_bf(*(const us8*)&Ksh[nt * 16 + l15][kf * 32 + quad * 8]);
          z4 = __builtin_amdgcn_mfma_f32_16x16x32_bf16(ka, qf[kf], z4, 0, 0, 0);
        }
        sf[nt] = z4 * cscale;
      }
      if (kt == j) {
        const int q = qc + l15;
#pragma unroll
        for (int nt = 0; nt < 4; nt++) {
          const int key0 = kbase + nt * 16 + quad * 4;
#pragma unroll
          for (int r = 0; r < 4; r++)
            if (key0 + r > q) sf[nt][r] = -INFINITY;
        }
      }
      float mx = sf[0][0];
#pragma unroll
      for (int nt = 0; nt < 4; nt++)
#pragma unroll
        for (int r = 0; r < 4; r++) mx = fmaxf(mx, sf[nt][r]);
      mx = fmaxf(mx, __shfl_xor(mx, 16, 64));
      mx = fmaxf(mx, __shfl_xor(mx, 32, 64));
      const float mnew = fmaxf(mrun, mx);
      const float alpha = exp2f(mrun - mnew);
      mrun = mnew;
      float rs = 0.f;
#pragma unroll
      for (int nt = 0; nt < 4; nt++) {
        us4 pk;
#pragma unroll
        for (int r = 0; r < 4; r++) {
          const float p = exp2f(sf[nt][r] - mnew);
          rs += p;
          pk[r] = f2bf(p);
        }
        *(us4*)&Pt[wave][l15][nt * 16 + quad * 4] = pk;
      }
      rs += __shfl_xor(rs, 16, 64);
      rs += __shfl_xor(rs, 32, 64);
      lrun = lrun * alpha + rs;
#pragma unroll
      for (int dt = 0; dt < 4; dt++) accO[dt] = accO[dt] * alpha;
      bf16x8 pf[2];
#pragma unroll
      for (int kk = 0; kk < 2; kk++)
        pf[kk] = as_bf(*(const us8*)&Pt[wave][l15][kk * 32 + quad * 8]);
#pragma unroll
      for (int dt = 0; dt < 4; dt++)
#pragma unroll
        for (int kk = 0; kk < 2; kk++) {
          const bf16x8 va = as_bf(*(const us8*)&Vsh[dt * 16 + l15][kk * 32 + quad * 8]);
          accO[dt] = __builtin_amdgcn_mfma_f32_16x16x32_bf16(va, pf[kk], accO[dt], 0, 0, 0);
        }
    }

    const float inv = 1.f / lrun;
#pragma unroll
    for (int dt = 0; dt < 4; dt++)
#pragma unroll
      for (int r = 0; r < 4; r++)
        Ot[wave][dt * 16 + quad * 4 + r][l15] = accO[dt][r] * inv;
    const int lq = lane >> 2, dbase = (lane & 3) * 16;
    us8 o0, o1;
#pragma unroll
    for (int i = 0; i < 8; i++) o0[i] = f2bf(Ot[wave][dbase + i][lq]);
#pragma unroll
    for (int i = 0; i < 8; i++) o1[i] = f2bf(Ot[wave][dbase + 8 + i][lq]);
    unsigned short* zp = Z + (size_t)(b * SEQ + qc + lq) * EMBED + h * 64 + dbase;
    *(us8*)zp = o0;
    *(us8*)(zp + 8) = o1;
  }
}

// ---------------------------------------------------------------------------
extern "C" void kernel_launch(void* const* d_in, const int* in_sizes, int n_in,
                              void* d_out, int out_size, void* d_ws, size_t ws_size,
                              hipStream_t stream) {
  const float* x   = (const float*)d_in[0];
  const float* Wq  = (const float*)d_in[1];
  const float* bq  = (const float*)d_in[2];
  const float* Wk  = (const float*)d_in[3];
  const float* bk  = (const float*)d_in[4];
  const float* Wv  = (const float*)d_in[5];
  const float* bv  = (const float*)d_in[6];
  const float* Wo  = (const float*)d_in[7];
  const float* W1  = (const float*)d_in[8];
  const float* b1  = (const float*)d_in[9];
  const float* W2  = (const float*)d_in[10];
  const float* b2  = (const float*)d_in[11];
  const float* g1  = (const float*)d_in[12];
  const float* be1 = (const float*)d_in[13];
  const float* g2  = (const float*)d_in[14];
  const float* be2 = (const float*)d_in[15];
  float* out = (float*)d_out;

  // Workspace map (MB offsets, 88 MB total):
  //  0- 8: wqT/wkT/wvT/woT  -> p0 (FF2 partial)
  //  8-16: w1T              -> p1
  // 16-24: w2T (live until FF2)
  // 24-32: ln1 -> zb (attn out) -> ln2 -> p2
  // 32-48: qb(32-40) + kb2(40-48) -> hb (fp32, after attn)
  // 48-56: vT -> pw0 (WO partial) -> p3
  // 56-88: m1 (56-64 doubles as pw1 before FF1)
  char* ws = (char*)d_ws;
  const size_t MB = 1024 * 1024;
  unsigned short* wqT = (unsigned short*)(ws + 0 * MB);
  unsigned short* wkT = (unsigned short*)(ws + 2 * MB);
  unsigned short* wvT = (unsigned short*)(ws + 4 * MB);
  unsigned short* woT = (unsigned short*)(ws + 6 * MB);
  unsigned short* w1T = (unsigned short*)(ws + 8 * MB);
  unsigned short* w2T = (unsigned short*)(ws + 16 * MB);
  unsigned short* ln1 = (unsigned short*)(ws + 24 * MB);
  unsigned short* zb  = (unsigned short*)(ws + 24 * MB);
  unsigned short* ln2 = (unsigned short*)(ws + 24 * MB);
  unsigned short* p2  = (unsigned short*)(ws + 24 * MB);
  unsigned short* qb  = (unsigned short*)(ws + 32 * MB);
  unsigned short* kb2 = (unsigned short*)(ws + 40 * MB);
  float*          hb  = (float*)         (ws + 32 * MB);
  unsigned short* vT  = (unsigned short*)(ws + 48 * MB);
  unsigned short* pw0 = (unsigned short*)(ws + 48 * MB);
  unsigned short* p3  = (unsigned short*)(ws + 48 * MB);
  unsigned short* pw1 = (unsigned short*)(ws + 56 * MB);
  unsigned short* m1  = (unsigned short*)(ws + 56 * MB);
  unsigned short* p0  = (unsigned short*)(ws + 0 * MB);
  unsigned short* p1  = (unsigned short*)(ws + 8 * MB);
  (void)in_sizes; (void)n_in; (void)out_size; (void)ws_size;

  transpose_all<<<12288, 256, 0, stream>>>(Wq, Wk, Wv, Wo, W1, W2,
                                           wqT, wkT, wvT, woT, w1T, w2T);

  layernorm_bf16<<<NROWS / 4, 256, 0, stream>>>(x, g1, be1, ln1);

  gemm_bf16<MODE_QKV, 32><<<dim3(8, 32, 3), 256, 0, stream>>>(
      ln1, wqT, wkT, wvT, bq, bk, bv, nullptr, qb, kb2, vT, nullptr,
      NROWS, 1024, 1024);

  attn_kernel<<<dim3(32, 16), 256, 0, stream>>>(qb, kb2, vT, zb);

  // WO: split-K=2 (NITER=16), bf16 partials; residual + LN fused below.
  gemm_bf16<MODE_PART, 16><<<dim3(8, 32, 2), 256, 0, stream>>>(
      zb, woT, nullptr, nullptr, nullptr, nullptr, nullptr, nullptr,
      pw0, pw1, nullptr, nullptr, NROWS, 1024, 1024);

  ln2_fused<<<NROWS / 4, 256, 0, stream>>>(x, pw0, pw1, g2, be2, hb, ln2);

  gemm_bf16<MODE_FF1, 32><<<dim3(32, 32), 256, 0, stream>>>(
      ln2, w1T, nullptr, nullptr, b1, nullptr, nullptr, nullptr,
      m1, nullptr, nullptr, nullptr, NROWS, 4096, 1024);

  // FF2: split-K=4 (NITER=32), bf16 partials, then reduce.
  gemm_bf16<MODE_PART, 32><<<dim3(8, 32, 4), 256, 0, stream>>>(
      m1, w2T, nullptr, nullptr, nullptr, nullptr, nullptr, nullptr,
      p0, p1, p2, p3, NROWS, 1024, 4096);

  ff2_reduce<<<NROWS * EMBED / (256 * 4), 256, 0, stream>>>(
      hb, b2, p0, p1, p2, p3, out);
}